// Round 2
// baseline (984.077 us; speedup 1.0000x reference)
//
#include <hip/hip_runtime.h>
#include <hip/hip_bf16.h>

#define NN 50000
#define EE 400000
#define GG 64
#define CAP 96

typedef unsigned short u16;

// bf16 <-> f32 used ONLY for internal workspace tensors (h1, h2pre, hL2).
__device__ __forceinline__ float b2f(u16 u) {
    unsigned int x = ((unsigned int)u) << 16;
    return __uint_as_float(x);
}
__device__ __forceinline__ u16 f2b(float f) {
    unsigned int x = __float_as_uint(f);
    unsigned int r = x + 0x7fffu + ((x >> 16) & 1u);
    return (u16)(r >> 16);
}
__device__ __forceinline__ float wred_sum(float v) {
    #pragma unroll
    for (int o = 32; o; o >>= 1) v += __shfl_xor(v, o, 64);
    return v;
}
__device__ __forceinline__ float wred_max(float v) {
    #pragma unroll
    for (int o = 32; o; o >>= 1) v = fmaxf(v, __shfl_xor(v, o, 64));
    return v;
}

// ---- init: degree=1 (self loop), seed CSR bucket with self loop, graph counts
__global__ void k_init(const int* __restrict__ batch, int* __restrict__ deg,
                       int* __restrict__ col, int* __restrict__ cnt) {
    int n = blockIdx.x * 256 + threadIdx.x;
    if (n < NN) {
        deg[n] = 1;
        col[(size_t)n * CAP] = n;
        atomicAdd(&cnt[batch[n]], 1);
    }
}

// ---- bucket-append edges by dst
__global__ void k_edges(const int* __restrict__ ei, int* __restrict__ deg,
                        int* __restrict__ col) {
    int e = blockIdx.x * 256 + threadIdx.x;
    if (e < EE) {
        int s = ei[e];
        int d = ei[EE + e];
        int slot = atomicAdd(&deg[d], 1);
        if (slot < CAP) col[(size_t)d * CAP + slot] = s;
    }
}

// ---- layer1 linear: h1 = x@W1 (bf16 out), fused a_src1/a_dst1 (fp32)
__global__ __launch_bounds__(256) void k_gemm1(
    const float* __restrict__ x, const float* __restrict__ W1,
    const float* __restrict__ as1, const float* __restrict__ ad1,
    u16* __restrict__ h1, float* __restrict__ a_src1, float* __restrict__ a_dst1) {
    __shared__ float xs[16];
    __shared__ float hb[512];
    int n = blockIdx.x, t = threadIdx.x;
    if (t < 16) xs[t] = x[n * 16 + t];
    __syncthreads();
    float h0 = 0.f, h1v = 0.f;
    #pragma unroll
    for (int k = 0; k < 16; k++) {
        float xv = xs[k];
        float2 wv = *(const float2*)(W1 + k * 512 + 2 * t);
        h0 += xv * wv.x;
        h1v += xv * wv.y;
    }
    ushort2 ov; ov.x = f2b(h0); ov.y = f2b(h1v);
    *(ushort2*)(h1 + (size_t)n * 512 + 2 * t) = ov;
    hb[2 * t] = h0; hb[2 * t + 1] = h1v;
    __syncthreads();
    int w = t >> 6, l = t & 63;
    float ss = 0.f, sd = 0.f;
    for (int c = l; c < 128; c += 64) {
        float hv = hb[w * 128 + c];
        ss += hv * as1[w * 128 + c];
        sd += hv * ad1[w * 128 + c];
    }
    ss = wred_sum(ss);
    sd = wred_sum(sd);
    if (l == 0) { a_src1[n * 4 + w] = ss; a_dst1[n * 4 + w] = sd; }
}

// ---- layer1 attention softmax + aggregation + bias + ELU -> h2pre (bf16)
__global__ __launch_bounds__(256) void k_agg1(
    const int* __restrict__ deg, const int* __restrict__ col,
    const float* __restrict__ a_src1, const float* __restrict__ a_dst1,
    const u16* __restrict__ h1, const float* __restrict__ b1,
    u16* __restrict__ h2pre) {
    __shared__ float ew[CAP * 4];
    __shared__ int scol[CAP];
    int n = blockIdx.x, t = threadIdx.x;
    int dg = min(deg[n], CAP);
    float ad0 = a_dst1[n * 4 + 0], ad1v = a_dst1[n * 4 + 1];
    float ad2v = a_dst1[n * 4 + 2], ad3v = a_dst1[n * 4 + 3];
    for (int j = t; j < dg; j += 256) {
        int s = col[(size_t)n * CAP + j];
        scol[j] = s;
        float4 av = *(const float4*)(a_src1 + s * 4);
        float v0 = av.x + ad0; ew[j * 4 + 0] = v0 > 0.f ? v0 : 0.2f * v0;
        float v1 = av.y + ad1v; ew[j * 4 + 1] = v1 > 0.f ? v1 : 0.2f * v1;
        float v2 = av.z + ad2v; ew[j * 4 + 2] = v2 > 0.f ? v2 : 0.2f * v2;
        float v3 = av.w + ad3v; ew[j * 4 + 3] = v3 > 0.f ? v3 : 0.2f * v3;
    }
    __syncthreads();
    int w = t >> 6, l = t & 63;
    // wave w computes softmax for head w
    float mx = -1e30f;
    for (int j = l; j < dg; j += 64) mx = fmaxf(mx, ew[j * 4 + w]);
    mx = wred_max(mx);
    float sm = 0.f;
    for (int j = l; j < dg; j += 64) {
        float ex = __expf(ew[j * 4 + w] - mx);
        ew[j * 4 + w] = ex;
        sm += ex;
    }
    sm = wred_sum(sm);
    float inv = 1.0f / sm;
    for (int j = l; j < dg; j += 64) ew[j * 4 + w] *= inv;
    __syncthreads();
    float acc0 = 0.f, acc1 = 0.f;
    int hh = t >> 6;  // channels 2t,2t+1 belong to head t/64
    for (int j = 0; j < dg; j++) {
        int s = scol[j];
        float al = ew[j * 4 + hh];
        ushort2 u = *(const ushort2*)(h1 + (size_t)s * 512 + 2 * t);
        acc0 += al * b2f(u.x);
        acc1 += al * b2f(u.y);
    }
    float o0 = acc0 + b1[2 * t];     o0 = o0 > 0.f ? o0 : __expf(o0) - 1.0f;
    float o1 = acc1 + b1[2 * t + 1]; o1 = o1 > 0.f ? o1 : __expf(o1) - 1.0f;
    ushort2 ov; ov.x = f2b(o0); ov.y = f2b(o1);
    *(ushort2*)(h2pre + (size_t)n * 512 + 2 * t) = ov;
}

// ---- layer2 linear: hL2 = h2pre@W2 (bf16 out), fused a_src2/a_dst2
#define NPB 8
__global__ __launch_bounds__(128) void k_gemm2(
    const u16* __restrict__ h2pre, const float* __restrict__ W2,
    const float* __restrict__ as2, const float* __restrict__ ad2,
    u16* __restrict__ hL2, float* __restrict__ a_src2, float* __restrict__ a_dst2) {
    __shared__ float4 hrow4[NPB][128];
    __shared__ float part[NPB * 2][2];
    float* hrow = (float*)hrow4;
    int t = threadIdx.x;
    int nb = blockIdx.x * NPB;
    for (int p = t; p < NPB * 256; p += 128) {
        int r = p >> 8, cc = (p & 255) * 2;
        ushort2 u = *(const ushort2*)(h2pre + (size_t)(nb + r) * 512 + cc);
        hrow[r * 512 + cc] = b2f(u.x);
        hrow[r * 512 + cc + 1] = b2f(u.y);
    }
    __syncthreads();
    float acc[NPB];
    #pragma unroll
    for (int r = 0; r < NPB; r++) acc[r] = 0.f;
    for (int k4 = 0; k4 < 128; k4++) {
        int k = k4 * 4;
        float w0 = W2[(k + 0) * 128 + t];
        float w1 = W2[(k + 1) * 128 + t];
        float w2 = W2[(k + 2) * 128 + t];
        float w3 = W2[(k + 3) * 128 + t];
        #pragma unroll
        for (int r = 0; r < NPB; r++) {
            float4 a = hrow4[r][k4];
            acc[r] += a.x * w0 + a.y * w1 + a.z * w2 + a.w * w3;
        }
    }
    float as2t = as2[t], ad2t = ad2[t];
    int w = t >> 6, l = t & 63;
    #pragma unroll
    for (int r = 0; r < NPB; r++) {
        hL2[(size_t)(nb + r) * 128 + t] = f2b(acc[r]);
        float ps = wred_sum(acc[r] * as2t);
        float pd = wred_sum(acc[r] * ad2t);
        if (l == 0) { part[r * 2 + 0][w] = ps; part[r * 2 + 1][w] = pd; }
    }
    __syncthreads();
    if (t < NPB * 2) {
        float v = part[t][0] + part[t][1];
        int r = t >> 1;
        if (t & 1) a_dst2[nb + r] = v; else a_src2[nb + r] = v;
    }
}

// ---- layer2 attention softmax + aggregation + bias + ELU -> h_final (fp32)
__global__ __launch_bounds__(128) void k_agg2(
    const int* __restrict__ deg, const int* __restrict__ col,
    const float* __restrict__ a_src2, const float* __restrict__ a_dst2,
    const u16* __restrict__ hL2, const float* __restrict__ b2v,
    float* __restrict__ hfin) {
    __shared__ float ew[CAP];
    __shared__ int scol[CAP];
    int n = blockIdx.x, t = threadIdx.x;
    int dg = min(deg[n], CAP);
    float ad = a_dst2[n];
    for (int j = t; j < dg; j += 128) {
        int s = col[(size_t)n * CAP + j];
        scol[j] = s;
        float v = a_src2[s] + ad;
        ew[j] = v > 0.f ? v : 0.2f * v;
    }
    __syncthreads();
    if (t < 64) {
        float mx = -1e30f;
        for (int j = t; j < dg; j += 64) mx = fmaxf(mx, ew[j]);
        mx = wred_max(mx);
        float sm = 0.f;
        for (int j = t; j < dg; j += 64) {
            float ex = __expf(ew[j] - mx);
            ew[j] = ex;
            sm += ex;
        }
        sm = wred_sum(sm);
        float inv = 1.0f / sm;
        for (int j = t; j < dg; j += 64) ew[j] *= inv;
    }
    __syncthreads();
    float acc = 0.f;
    for (int j = 0; j < dg; j++) acc += ew[j] * b2f(hL2[(size_t)scol[j] * 128 + t]);
    float o = acc + b2v[t];
    o = o > 0.f ? o : __expf(o) - 1.0f;
    hfin[(size_t)n * 128 + t] = o;
}

// ---- trivial scan of 64 graph counts
__global__ void k_gscan(const int* __restrict__ cnt, int* __restrict__ gstart) {
    if (threadIdx.x == 0) {
        int s = 0;
        for (int g = 0; g < GG; g++) { gstart[g] = s; s += cnt[g]; }
        gstart[GG] = s;
    }
}

// ---- mean pool + graph MLP + classifier
__global__ __launch_bounds__(128) void k_head(
    const int* __restrict__ gstart, const float* __restrict__ hfin,
    const float* __restrict__ gfeat,
    const float* __restrict__ Wg1, const float* __restrict__ bg1,
    const float* __restrict__ Wg2, const float* __restrict__ bg2,
    const float* __restrict__ Wc1, const float* __restrict__ bc1,
    const float* __restrict__ Wc2, const float* __restrict__ bc2,
    float* __restrict__ out) {
    __shared__ float z[160];
    __shared__ float hg[32];
    __shared__ float c1b[128];
    int g = blockIdx.x, t = threadIdx.x;
    int s0 = gstart[g], s1 = gstart[g + 1];
    float acc = 0.f;
    for (int n = s0; n < s1; n++) acc += hfin[(size_t)n * 128 + t];
    float cntf = (float)(s1 - s0);
    z[t] = acc / fmaxf(cntf, 1.0f);
    if (t < 32) {
        float a = bg1[t];
        for (int i = 0; i < 10; i++) a += gfeat[g * 10 + i] * Wg1[i * 32 + t];
        hg[t] = fmaxf(a, 0.f);
    }
    __syncthreads();
    if (t < 32) {
        float a = bg2[t];
        for (int i = 0; i < 32; i++) a += hg[i] * Wg2[i * 32 + t];
        z[128 + t] = a;
    }
    __syncthreads();
    float a = bc1[t];
    for (int i = 0; i < 160; i++) a += z[i] * Wc1[i * 128 + t];
    c1b[t] = fmaxf(a, 0.f);
    __syncthreads();
    if (t < 6) {
        float o = bc2[t];
        for (int i = 0; i < 128; i++) o += c1b[i] * Wc2[i * 6 + t];
        out[g * 6 + t] = o;
    }
}

extern "C" void kernel_launch(void* const* d_in, const int* in_sizes, int n_in,
                              void* d_out, int out_size, void* d_ws, size_t ws_size,
                              hipStream_t stream) {
    const float* x     = (const float*)d_in[0];
    const int*   ei    = (const int*)d_in[1];
    const int*   batch = (const int*)d_in[2];
    const float* gfeat = (const float*)d_in[3];
    const float* W1    = (const float*)d_in[4];
    const float* as1   = (const float*)d_in[5];
    const float* ad1   = (const float*)d_in[6];
    const float* b1    = (const float*)d_in[7];
    const float* W2    = (const float*)d_in[8];
    const float* as2   = (const float*)d_in[9];
    const float* ad2   = (const float*)d_in[10];
    const float* b2    = (const float*)d_in[11];
    const float* Wg1   = (const float*)d_in[12];
    const float* bg1   = (const float*)d_in[13];
    const float* Wg2   = (const float*)d_in[14];
    const float* bg2   = (const float*)d_in[15];
    const float* Wc1   = (const float*)d_in[16];
    const float* bc1   = (const float*)d_in[17];
    const float* Wc2   = (const float*)d_in[18];
    const float* bc2   = (const float*)d_in[19];
    float* out = (float*)d_out;

    // workspace layout (256B aligned slices); total ~162 MB
    size_t off = 0;
    char* base = (char*)d_ws;
    auto take = [&](size_t nbytes) -> char* {
        char* p = base + off;
        off = (off + nbytes + 255) & ~(size_t)255;
        return p;
    };
    u16*   h1     = (u16*)take((size_t)NN * 512 * 2);
    u16*   h2pre  = (u16*)take((size_t)NN * 512 * 2);
    u16*   hL2    = (u16*)take((size_t)NN * 128 * 2);
    float* hfin   = (float*)take((size_t)NN * 128 * 4);
    float* a_src1 = (float*)take((size_t)NN * 4 * 4);
    float* a_dst1 = (float*)take((size_t)NN * 4 * 4);
    float* a_src2 = (float*)take((size_t)NN * 4);
    float* a_dst2 = (float*)take((size_t)NN * 4);
    int*   deg    = (int*)take((size_t)NN * 4);
    int*   col    = (int*)take((size_t)NN * CAP * 4);
    int*   cnt    = (int*)take(GG * 4);
    int*   gstart = (int*)take((GG + 1) * 4);
    (void)ws_size; (void)in_sizes; (void)n_in; (void)out_size;

    hipMemsetAsync(cnt, 0, GG * 4, stream);
    k_init<<<(NN + 255) / 256, 256, 0, stream>>>(batch, deg, col, cnt);
    k_edges<<<(EE + 255) / 256, 256, 0, stream>>>(ei, deg, col);
    k_gemm1<<<NN, 256, 0, stream>>>(x, W1, as1, ad1, h1, a_src1, a_dst1);
    k_agg1<<<NN, 256, 0, stream>>>(deg, col, a_src1, a_dst1, h1, b1, h2pre);
    k_gemm2<<<NN / NPB, 128, 0, stream>>>(h2pre, W2, as2, ad2, hL2, a_src2, a_dst2);
    k_agg2<<<NN, 128, 0, stream>>>(deg, col, a_src2, a_dst2, hL2, b2, hfin);
    k_gscan<<<1, 64, 0, stream>>>(cnt, gstart);
    k_head<<<GG, 128, 0, stream>>>(gstart, hfin, gfeat, Wg1, bg1, Wg2, bg2,
                                   Wc1, bc1, Wc2, bc2, out);
}

// Round 3
// 573.844 us; speedup vs baseline: 1.7149x; 1.7149x over previous
//
#include <hip/hip_runtime.h>
#include <hip/hip_bf16.h>

#define NN 50000
#define EE 400000
#define GG 64
#define CAP 96
#define SPLIT 16

typedef unsigned short u16;

// bf16 <-> f32 used ONLY for internal workspace tensors (h1, h2pre, hL2).
__device__ __forceinline__ float b2f(u16 u) {
    unsigned int x = ((unsigned int)u) << 16;
    return __uint_as_float(x);
}
__device__ __forceinline__ u16 f2b(float f) {
    unsigned int x = __float_as_uint(f);
    unsigned int r = x + 0x7fffu + ((x >> 16) & 1u);
    return (u16)(r >> 16);
}
__device__ __forceinline__ float wred_sum(float v) {
    #pragma unroll
    for (int o = 32; o; o >>= 1) v += __shfl_xor(v, o, 64);
    return v;
}
__device__ __forceinline__ float wred_max(float v) {
    #pragma unroll
    for (int o = 32; o; o >>= 1) v = fmaxf(v, __shfl_xor(v, o, 64));
    return v;
}

// ---- init: degree=1 (self loop), seed CSR bucket with self loop. NO atomics.
__global__ void k_init(int* __restrict__ deg, int* __restrict__ col) {
    int n = blockIdx.x * 256 + threadIdx.x;
    if (n < NN) {
        deg[n] = 1;
        col[(size_t)n * CAP] = n;
    }
}

// ---- graph segment starts via binary search over sorted batch (no atomics)
__global__ void k_gstart(const int* __restrict__ batch, int* __restrict__ gstart) {
    int g = threadIdx.x;
    if (g <= GG) {
        // first index n with batch[n] >= g
        int lo = 0, hi = NN;
        while (lo < hi) {
            int mid = (lo + hi) >> 1;
            if (batch[mid] < g) lo = mid + 1; else hi = mid;
        }
        gstart[g] = lo;
    }
}

// ---- bucket-append edges by dst
__global__ void k_edges(const int* __restrict__ ei, int* __restrict__ deg,
                        int* __restrict__ col) {
    int e = blockIdx.x * 256 + threadIdx.x;
    if (e < EE) {
        int s = ei[e];
        int d = ei[EE + e];
        int slot = atomicAdd(&deg[d], 1);
        if (slot < CAP) col[(size_t)d * CAP + slot] = s;
    }
}

// ---- layer1 linear: h1 = x@W1 (bf16 out), fused a_src1/a_dst1 (fp32)
__global__ __launch_bounds__(256) void k_gemm1(
    const float* __restrict__ x, const float* __restrict__ W1,
    const float* __restrict__ as1, const float* __restrict__ ad1,
    u16* __restrict__ h1, float* __restrict__ a_src1, float* __restrict__ a_dst1) {
    __shared__ float xs[16];
    __shared__ float hb[512];
    int n = blockIdx.x, t = threadIdx.x;
    if (t < 16) xs[t] = x[n * 16 + t];
    __syncthreads();
    float h0 = 0.f, h1v = 0.f;
    #pragma unroll
    for (int k = 0; k < 16; k++) {
        float xv = xs[k];
        float2 wv = *(const float2*)(W1 + k * 512 + 2 * t);
        h0 += xv * wv.x;
        h1v += xv * wv.y;
    }
    ushort2 ov; ov.x = f2b(h0); ov.y = f2b(h1v);
    *(ushort2*)(h1 + (size_t)n * 512 + 2 * t) = ov;
    hb[2 * t] = h0; hb[2 * t + 1] = h1v;
    __syncthreads();
    int w = t >> 6, l = t & 63;
    float ss = 0.f, sd = 0.f;
    for (int c = l; c < 128; c += 64) {
        float hv = hb[w * 128 + c];
        ss += hv * as1[w * 128 + c];
        sd += hv * ad1[w * 128 + c];
    }
    ss = wred_sum(ss);
    sd = wred_sum(sd);
    if (l == 0) { a_src1[n * 4 + w] = ss; a_dst1[n * 4 + w] = sd; }
}

// ---- layer1 attention softmax + aggregation + bias + ELU -> h2pre (bf16)
__global__ __launch_bounds__(256) void k_agg1(
    const int* __restrict__ deg, const int* __restrict__ col,
    const float* __restrict__ a_src1, const float* __restrict__ a_dst1,
    const u16* __restrict__ h1, const float* __restrict__ b1,
    u16* __restrict__ h2pre) {
    __shared__ float ew[CAP * 4];
    __shared__ int scol[CAP];
    int n = blockIdx.x, t = threadIdx.x;
    int dg = min(deg[n], CAP);
    float ad0 = a_dst1[n * 4 + 0], ad1v = a_dst1[n * 4 + 1];
    float ad2v = a_dst1[n * 4 + 2], ad3v = a_dst1[n * 4 + 3];
    for (int j = t; j < dg; j += 256) {
        int s = col[(size_t)n * CAP + j];
        scol[j] = s;
        float4 av = *(const float4*)(a_src1 + s * 4);
        float v0 = av.x + ad0; ew[j * 4 + 0] = v0 > 0.f ? v0 : 0.2f * v0;
        float v1 = av.y + ad1v; ew[j * 4 + 1] = v1 > 0.f ? v1 : 0.2f * v1;
        float v2 = av.z + ad2v; ew[j * 4 + 2] = v2 > 0.f ? v2 : 0.2f * v2;
        float v3 = av.w + ad3v; ew[j * 4 + 3] = v3 > 0.f ? v3 : 0.2f * v3;
    }
    __syncthreads();
    int w = t >> 6, l = t & 63;
    // wave w computes softmax for head w
    float mx = -1e30f;
    for (int j = l; j < dg; j += 64) mx = fmaxf(mx, ew[j * 4 + w]);
    mx = wred_max(mx);
    float sm = 0.f;
    for (int j = l; j < dg; j += 64) {
        float ex = __expf(ew[j * 4 + w] - mx);
        ew[j * 4 + w] = ex;
        sm += ex;
    }
    sm = wred_sum(sm);
    float inv = 1.0f / sm;
    for (int j = l; j < dg; j += 64) ew[j * 4 + w] *= inv;
    __syncthreads();
    float acc0 = 0.f, acc1 = 0.f;
    int hh = t >> 6;  // channels 2t,2t+1 belong to head t/64
    for (int j = 0; j < dg; j++) {
        int s = scol[j];
        float al = ew[j * 4 + hh];
        ushort2 u = *(const ushort2*)(h1 + (size_t)s * 512 + 2 * t);
        acc0 += al * b2f(u.x);
        acc1 += al * b2f(u.y);
    }
    float o0 = acc0 + b1[2 * t];     o0 = o0 > 0.f ? o0 : __expf(o0) - 1.0f;
    float o1 = acc1 + b1[2 * t + 1]; o1 = o1 > 0.f ? o1 : __expf(o1) - 1.0f;
    ushort2 ov; ov.x = f2b(o0); ov.y = f2b(o1);
    *(ushort2*)(h2pre + (size_t)n * 512 + 2 * t) = ov;
}

// ---- layer2 linear: hL2 = h2pre@W2 (bf16 out), fused a_src2/a_dst2
#define NPB 8
__global__ __launch_bounds__(128) void k_gemm2(
    const u16* __restrict__ h2pre, const float* __restrict__ W2,
    const float* __restrict__ as2, const float* __restrict__ ad2,
    u16* __restrict__ hL2, float* __restrict__ a_src2, float* __restrict__ a_dst2) {
    __shared__ float4 hrow4[NPB][128];
    __shared__ float part[NPB * 2][2];
    float* hrow = (float*)hrow4;
    int t = threadIdx.x;
    int nb = blockIdx.x * NPB;
    for (int p = t; p < NPB * 256; p += 128) {
        int r = p >> 8, cc = (p & 255) * 2;
        ushort2 u = *(const ushort2*)(h2pre + (size_t)(nb + r) * 512 + cc);
        hrow[r * 512 + cc] = b2f(u.x);
        hrow[r * 512 + cc + 1] = b2f(u.y);
    }
    __syncthreads();
    float acc[NPB];
    #pragma unroll
    for (int r = 0; r < NPB; r++) acc[r] = 0.f;
    for (int k4 = 0; k4 < 128; k4++) {
        int k = k4 * 4;
        float w0 = W2[(k + 0) * 128 + t];
        float w1 = W2[(k + 1) * 128 + t];
        float w2 = W2[(k + 2) * 128 + t];
        float w3 = W2[(k + 3) * 128 + t];
        #pragma unroll
        for (int r = 0; r < NPB; r++) {
            float4 a = hrow4[r][k4];
            acc[r] += a.x * w0 + a.y * w1 + a.z * w2 + a.w * w3;
        }
    }
    float as2t = as2[t], ad2t = ad2[t];
    int w = t >> 6, l = t & 63;
    #pragma unroll
    for (int r = 0; r < NPB; r++) {
        hL2[(size_t)(nb + r) * 128 + t] = f2b(acc[r]);
        float ps = wred_sum(acc[r] * as2t);
        float pd = wred_sum(acc[r] * ad2t);
        if (l == 0) { part[r * 2 + 0][w] = ps; part[r * 2 + 1][w] = pd; }
    }
    __syncthreads();
    if (t < NPB * 2) {
        float v = part[t][0] + part[t][1];
        int r = t >> 1;
        if (t & 1) a_dst2[nb + r] = v; else a_src2[nb + r] = v;
    }
}

// ---- layer2 attention softmax + aggregation + bias + ELU -> h_final (fp32)
__global__ __launch_bounds__(128) void k_agg2(
    const int* __restrict__ deg, const int* __restrict__ col,
    const float* __restrict__ a_src2, const float* __restrict__ a_dst2,
    const u16* __restrict__ hL2, const float* __restrict__ b2v,
    float* __restrict__ hfin) {
    __shared__ float ew[CAP];
    __shared__ int scol[CAP];
    int n = blockIdx.x, t = threadIdx.x;
    int dg = min(deg[n], CAP);
    float ad = a_dst2[n];
    for (int j = t; j < dg; j += 128) {
        int s = col[(size_t)n * CAP + j];
        scol[j] = s;
        float v = a_src2[s] + ad;
        ew[j] = v > 0.f ? v : 0.2f * v;
    }
    __syncthreads();
    if (t < 64) {
        float mx = -1e30f;
        for (int j = t; j < dg; j += 64) mx = fmaxf(mx, ew[j]);
        mx = wred_max(mx);
        float sm = 0.f;
        for (int j = t; j < dg; j += 64) {
            float ex = __expf(ew[j] - mx);
            ew[j] = ex;
            sm += ex;
        }
        sm = wred_sum(sm);
        float inv = 1.0f / sm;
        for (int j = t; j < dg; j += 64) ew[j] *= inv;
    }
    __syncthreads();
    float acc = 0.f;
    for (int j = 0; j < dg; j++) acc += ew[j] * b2f(hL2[(size_t)scol[j] * 128 + t]);
    float o = acc + b2v[t];
    o = o > 0.f ? o : __expf(o) - 1.0f;
    hfin[(size_t)n * 128 + t] = o;
}

// ---- parallel mean-pool partials: grid GG*SPLIT, atomicAdd into pooled
__global__ __launch_bounds__(128) void k_pool(
    const int* __restrict__ gstart, const float* __restrict__ hfin,
    float* __restrict__ pooled) {
    int g = blockIdx.x / SPLIT, i = blockIdx.x % SPLIT, t = threadIdx.x;
    int s0 = gstart[g], s1 = gstart[g + 1];
    int len = s1 - s0;
    int chunk = (len + SPLIT - 1) / SPLIT;
    int a = s0 + i * chunk;
    int b = min(a + chunk, s1);
    if (a >= b) return;
    float acc = 0.f;
    for (int n = a; n < b; n++) acc += hfin[(size_t)n * 128 + t];
    atomicAdd(&pooled[g * 128 + t], acc);
}

// ---- graph MLP + classifier (pooled already summed)
__global__ __launch_bounds__(128) void k_head(
    const int* __restrict__ gstart, const float* __restrict__ pooled,
    const float* __restrict__ gfeat,
    const float* __restrict__ Wg1, const float* __restrict__ bg1,
    const float* __restrict__ Wg2, const float* __restrict__ bg2,
    const float* __restrict__ Wc1, const float* __restrict__ bc1,
    const float* __restrict__ Wc2, const float* __restrict__ bc2,
    float* __restrict__ out) {
    __shared__ float z[160];
    __shared__ float hg[32];
    __shared__ float c1b[128];
    int g = blockIdx.x, t = threadIdx.x;
    float cntf = (float)(gstart[g + 1] - gstart[g]);
    z[t] = pooled[g * 128 + t] / fmaxf(cntf, 1.0f);
    if (t < 32) {
        float a = bg1[t];
        for (int i = 0; i < 10; i++) a += gfeat[g * 10 + i] * Wg1[i * 32 + t];
        hg[t] = fmaxf(a, 0.f);
    }
    __syncthreads();
    if (t < 32) {
        float a = bg2[t];
        for (int i = 0; i < 32; i++) a += hg[i] * Wg2[i * 32 + t];
        z[128 + t] = a;
    }
    __syncthreads();
    float a = bc1[t];
    for (int i = 0; i < 160; i++) a += z[i] * Wc1[i * 128 + t];
    c1b[t] = fmaxf(a, 0.f);
    __syncthreads();
    if (t < 6) {
        float o = bc2[t];
        for (int i = 0; i < 128; i++) o += c1b[i] * Wc2[i * 6 + t];
        out[g * 6 + t] = o;
    }
}

extern "C" void kernel_launch(void* const* d_in, const int* in_sizes, int n_in,
                              void* d_out, int out_size, void* d_ws, size_t ws_size,
                              hipStream_t stream) {
    const float* x     = (const float*)d_in[0];
    const int*   ei    = (const int*)d_in[1];
    const int*   batch = (const int*)d_in[2];
    const float* gfeat = (const float*)d_in[3];
    const float* W1    = (const float*)d_in[4];
    const float* as1   = (const float*)d_in[5];
    const float* ad1   = (const float*)d_in[6];
    const float* b1    = (const float*)d_in[7];
    const float* W2    = (const float*)d_in[8];
    const float* as2   = (const float*)d_in[9];
    const float* ad2   = (const float*)d_in[10];
    const float* b2    = (const float*)d_in[11];
    const float* Wg1   = (const float*)d_in[12];
    const float* bg1   = (const float*)d_in[13];
    const float* Wg2   = (const float*)d_in[14];
    const float* bg2   = (const float*)d_in[15];
    const float* Wc1   = (const float*)d_in[16];
    const float* bc1   = (const float*)d_in[17];
    const float* Wc2   = (const float*)d_in[18];
    const float* bc2   = (const float*)d_in[19];
    float* out = (float*)d_out;

    // workspace layout (256B aligned slices); total ~162 MB
    size_t off = 0;
    char* base = (char*)d_ws;
    auto take = [&](size_t nbytes) -> char* {
        char* p = base + off;
        off = (off + nbytes + 255) & ~(size_t)255;
        return p;
    };
    u16*   h1     = (u16*)take((size_t)NN * 512 * 2);
    u16*   h2pre  = (u16*)take((size_t)NN * 512 * 2);
    u16*   hL2    = (u16*)take((size_t)NN * 128 * 2);
    float* hfin   = (float*)take((size_t)NN * 128 * 4);
    float* a_src1 = (float*)take((size_t)NN * 4 * 4);
    float* a_dst1 = (float*)take((size_t)NN * 4 * 4);
    float* a_src2 = (float*)take((size_t)NN * 4);
    float* a_dst2 = (float*)take((size_t)NN * 4);
    int*   deg    = (int*)take((size_t)NN * 4);
    int*   col    = (int*)take((size_t)NN * CAP * 4);
    float* pooled = (float*)take(GG * 128 * 4);
    int*   gstart = (int*)take((GG + 1) * 4);
    (void)ws_size; (void)in_sizes; (void)n_in; (void)out_size;

    hipMemsetAsync(pooled, 0, GG * 128 * 4, stream);
    k_init<<<(NN + 255) / 256, 256, 0, stream>>>(deg, col);
    k_gstart<<<1, 128, 0, stream>>>(batch, gstart);
    k_edges<<<(EE + 255) / 256, 256, 0, stream>>>(ei, deg, col);
    k_gemm1<<<NN, 256, 0, stream>>>(x, W1, as1, ad1, h1, a_src1, a_dst1);
    k_agg1<<<NN, 256, 0, stream>>>(deg, col, a_src1, a_dst1, h1, b1, h2pre);
    k_gemm2<<<NN / NPB, 128, 0, stream>>>(h2pre, W2, as2, ad2, hL2, a_src2, a_dst2);
    k_agg2<<<NN, 128, 0, stream>>>(deg, col, a_src2, a_dst2, hL2, b2, hfin);
    k_pool<<<GG * SPLIT, 128, 0, stream>>>(gstart, hfin, pooled);
    k_head<<<GG, 128, 0, stream>>>(gstart, pooled, gfeat, Wg1, bg1, Wg2, bg2,
                                   Wc1, bc1, Wc2, bc2, out);
}

// Round 4
// 442.729 us; speedup vs baseline: 2.2228x; 1.2962x over previous
//
#include <hip/hip_runtime.h>
#include <hip/hip_bf16.h>

#define NN 50000
#define EE 400000
#define GG 64
#define CAP 96
#define SPLIT 16

typedef unsigned short u16;
typedef __attribute__((ext_vector_type(8))) short bf16x8;
typedef __attribute__((ext_vector_type(4))) float f32x4;

// bf16 <-> f32 used ONLY for internal workspace tensors (h1, h2pre, hL2, W2p).
__device__ __forceinline__ float b2f(u16 u) {
    unsigned int x = ((unsigned int)u) << 16;
    return __uint_as_float(x);
}
__device__ __forceinline__ u16 f2b(float f) {
    unsigned int x = __float_as_uint(f);
    unsigned int r = x + 0x7fffu + ((x >> 16) & 1u);
    return (u16)(r >> 16);
}
__device__ __forceinline__ float wred_sum(float v) {
    #pragma unroll
    for (int o = 32; o; o >>= 1) v += __shfl_xor(v, o, 64);
    return v;
}
__device__ __forceinline__ float wred_max(float v) {
    #pragma unroll
    for (int o = 32; o; o >>= 1) v = fmaxf(v, __shfl_xor(v, o, 64));
    return v;
}

// ---- init: degree=1 (self loop), seed CSR bucket with self loop. NO atomics.
__global__ void k_init(int* __restrict__ deg, int* __restrict__ col) {
    int n = blockIdx.x * 256 + threadIdx.x;
    if (n < NN) {
        deg[n] = 1;
        col[(size_t)n * CAP] = n;
    }
}

// ---- graph segment starts via binary search over sorted batch (no atomics)
__global__ void k_gstart(const int* __restrict__ batch, int* __restrict__ gstart) {
    int g = threadIdx.x;
    if (g <= GG) {
        int lo = 0, hi = NN;
        while (lo < hi) {
            int mid = (lo + hi) >> 1;
            if (batch[mid] < g) lo = mid + 1; else hi = mid;
        }
        gstart[g] = lo;
    }
}

// ---- bucket-append edges by dst
__global__ void k_edges(const int* __restrict__ ei, int* __restrict__ deg,
                        int* __restrict__ col) {
    int e = blockIdx.x * 256 + threadIdx.x;
    if (e < EE) {
        int s = ei[e];
        int d = ei[EE + e];
        int slot = atomicAdd(&deg[d], 1);
        if (slot < CAP) col[(size_t)d * CAP + slot] = s;
    }
}

// ---- pack W2 (fp32 [512][128]) into bf16 MFMA B-fragment order.
// W2p[((c*8+t)*64 + l)*8 + j] = W2[k][n], k=c*32+(l>>4)*8+j, n=t*16+(l&15)
__global__ void k_cvtW2(const float* __restrict__ W2, u16* __restrict__ W2p) {
    int idx = blockIdx.x * 256 + threadIdx.x;  // 65536 total
    int j = idx & 7;
    int l = (idx >> 3) & 63;
    int ct = idx >> 9;        // c*8+t
    int c = ct >> 3, tt = ct & 7;
    int k = c * 32 + (l >> 4) * 8 + j;
    int n = tt * 16 + (l & 15);
    W2p[idx] = f2b(W2[k * 128 + n]);
}

// ---- layer1 linear: h1 = x@W1 (bf16 out), fused a_src1/a_dst1 (fp32)
__global__ __launch_bounds__(256) void k_gemm1(
    const float* __restrict__ x, const float* __restrict__ W1,
    const float* __restrict__ as1, const float* __restrict__ ad1,
    u16* __restrict__ h1, float* __restrict__ a_src1, float* __restrict__ a_dst1) {
    __shared__ float xs[16];
    __shared__ float hb[512];
    int n = blockIdx.x, t = threadIdx.x;
    if (t < 16) xs[t] = x[n * 16 + t];
    __syncthreads();
    float h0 = 0.f, h1v = 0.f;
    #pragma unroll
    for (int k = 0; k < 16; k++) {
        float xv = xs[k];
        float2 wv = *(const float2*)(W1 + k * 512 + 2 * t);
        h0 += xv * wv.x;
        h1v += xv * wv.y;
    }
    ushort2 ov; ov.x = f2b(h0); ov.y = f2b(h1v);
    *(ushort2*)(h1 + (size_t)n * 512 + 2 * t) = ov;
    hb[2 * t] = h0; hb[2 * t + 1] = h1v;
    __syncthreads();
    int w = t >> 6, l = t & 63;
    float ss = 0.f, sd = 0.f;
    for (int c = l; c < 128; c += 64) {
        float hv = hb[w * 128 + c];
        ss += hv * as1[w * 128 + c];
        sd += hv * ad1[w * 128 + c];
    }
    ss = wred_sum(ss);
    sd = wred_sum(sd);
    if (l == 0) { a_src1[n * 4 + w] = ss; a_dst1[n * 4 + w] = sd; }
}

// ---- layer1 attention softmax + aggregation + bias + ELU -> h2pre (bf16)
__global__ __launch_bounds__(256) void k_agg1(
    const int* __restrict__ deg, const int* __restrict__ col,
    const float* __restrict__ a_src1, const float* __restrict__ a_dst1,
    const u16* __restrict__ h1, const float* __restrict__ b1,
    u16* __restrict__ h2pre) {
    __shared__ float ew[CAP * 4];
    __shared__ int scol[CAP];
    int n = blockIdx.x, t = threadIdx.x;
    int dg = min(deg[n], CAP);
    float ad0 = a_dst1[n * 4 + 0], ad1v = a_dst1[n * 4 + 1];
    float ad2v = a_dst1[n * 4 + 2], ad3v = a_dst1[n * 4 + 3];
    for (int j = t; j < dg; j += 256) {
        int s = col[(size_t)n * CAP + j];
        scol[j] = s;
        float4 av = *(const float4*)(a_src1 + s * 4);
        float v0 = av.x + ad0; ew[j * 4 + 0] = v0 > 0.f ? v0 : 0.2f * v0;
        float v1 = av.y + ad1v; ew[j * 4 + 1] = v1 > 0.f ? v1 : 0.2f * v1;
        float v2 = av.z + ad2v; ew[j * 4 + 2] = v2 > 0.f ? v2 : 0.2f * v2;
        float v3 = av.w + ad3v; ew[j * 4 + 3] = v3 > 0.f ? v3 : 0.2f * v3;
    }
    __syncthreads();
    int w = t >> 6, l = t & 63;
    float mx = -1e30f;
    for (int j = l; j < dg; j += 64) mx = fmaxf(mx, ew[j * 4 + w]);
    mx = wred_max(mx);
    float sm = 0.f;
    for (int j = l; j < dg; j += 64) {
        float ex = __expf(ew[j * 4 + w] - mx);
        ew[j * 4 + w] = ex;
        sm += ex;
    }
    sm = wred_sum(sm);
    float inv = 1.0f / sm;
    for (int j = l; j < dg; j += 64) ew[j * 4 + w] *= inv;
    __syncthreads();
    float acc0 = 0.f, acc1 = 0.f;
    int hh = t >> 6;
    for (int j = 0; j < dg; j++) {
        int s = scol[j];
        float al = ew[j * 4 + hh];
        ushort2 u = *(const ushort2*)(h1 + (size_t)s * 512 + 2 * t);
        acc0 += al * b2f(u.x);
        acc1 += al * b2f(u.y);
    }
    float o0 = acc0 + b1[2 * t];     o0 = o0 > 0.f ? o0 : __expf(o0) - 1.0f;
    float o1 = acc1 + b1[2 * t + 1]; o1 = o1 > 0.f ? o1 : __expf(o1) - 1.0f;
    ushort2 ov; ov.x = f2b(o0); ov.y = f2b(o1);
    *(ushort2*)(h2pre + (size_t)n * 512 + 2 * t) = ov;
}

// ---- layer2 linear via MFMA: hL2 = h2pre@W2 (bf16), fused a_src2/a_dst2.
// Block = 4 waves; wave computes rows [row0,row0+16) x all 128 cols.
// A-frag: lane l loads h2pre[row0+(l&15)][c*32+(l>>4)*8 .. +7] (16B, direct global).
// B-frag: packed W2p, 16B contiguous per lane.
// C/D: col=lane&15, row=(lane>>4)*4+reg.
__global__ __launch_bounds__(256) void k_gemm2(
    const u16* __restrict__ h2pre, const u16* __restrict__ W2p,
    const float* __restrict__ as2, const float* __restrict__ ad2,
    u16* __restrict__ hL2, float* __restrict__ a_src2, float* __restrict__ a_dst2) {
    int t = threadIdx.x;
    int wave = t >> 6, l = t & 63;
    int quad = l >> 4, m = l & 15;
    int row0 = blockIdx.x * 64 + wave * 16;
    int arow = row0 + m;
    int arow_c = arow < NN ? arow : (NN - 1);
    const u16* aptr = h2pre + (size_t)arow_c * 512 + quad * 8;
    const u16* bptr = W2p + l * 8;
    f32x4 acc[8];
    #pragma unroll
    for (int tt = 0; tt < 8; tt++) acc[tt] = (f32x4){0.f, 0.f, 0.f, 0.f};
    for (int c = 0; c < 16; c++) {
        bf16x8 af = *(const bf16x8*)(aptr + c * 32);
        #pragma unroll
        for (int tt = 0; tt < 8; tt++) {
            bf16x8 bf = *(const bf16x8*)(bptr + (size_t)(c * 8 + tt) * 512);
            acc[tt] = __builtin_amdgcn_mfma_f32_16x16x32_bf16(af, bf, acc[tt], 0, 0, 0);
        }
    }
    // preload attention vectors for this lane's 8 columns
    float asv[8], adv[8];
    #pragma unroll
    for (int tt = 0; tt < 8; tt++) {
        int colc = tt * 16 + m;
        asv[tt] = as2[colc];
        adv[tt] = ad2[colc];
    }
    #pragma unroll
    for (int r = 0; r < 4; r++) {
        int row = row0 + quad * 4 + r;
        bool ok = row < NN;
        float rs = 0.f, rd = 0.f;
        #pragma unroll
        for (int tt = 0; tt < 8; tt++) {
            float v = acc[tt][r];
            if (ok) hL2[(size_t)row * 128 + tt * 16 + m] = f2b(v);
            rs += v * asv[tt];
            rd += v * adv[tt];
        }
        #pragma unroll
        for (int o = 1; o < 16; o <<= 1) {
            rs += __shfl_xor(rs, o, 64);
            rd += __shfl_xor(rd, o, 64);
        }
        if (ok && m == 0) { a_src2[row] = rs; a_dst2[row] = rd; }
    }
}

// ---- layer2 attention softmax + aggregation + bias + ELU -> h_final (fp32)
__global__ __launch_bounds__(128) void k_agg2(
    const int* __restrict__ deg, const int* __restrict__ col,
    const float* __restrict__ a_src2, const float* __restrict__ a_dst2,
    const u16* __restrict__ hL2, const float* __restrict__ b2v,
    float* __restrict__ hfin) {
    __shared__ float ew[CAP];
    __shared__ int scol[CAP];
    int n = blockIdx.x, t = threadIdx.x;
    int dg = min(deg[n], CAP);
    float ad = a_dst2[n];
    for (int j = t; j < dg; j += 128) {
        int s = col[(size_t)n * CAP + j];
        scol[j] = s;
        float v = a_src2[s] + ad;
        ew[j] = v > 0.f ? v : 0.2f * v;
    }
    __syncthreads();
    if (t < 64) {
        float mx = -1e30f;
        for (int j = t; j < dg; j += 64) mx = fmaxf(mx, ew[j]);
        mx = wred_max(mx);
        float sm = 0.f;
        for (int j = t; j < dg; j += 64) {
            float ex = __expf(ew[j] - mx);
            ew[j] = ex;
            sm += ex;
        }
        sm = wred_sum(sm);
        float inv = 1.0f / sm;
        for (int j = t; j < dg; j += 64) ew[j] *= inv;
    }
    __syncthreads();
    float acc = 0.f;
    for (int j = 0; j < dg; j++) acc += ew[j] * b2f(hL2[(size_t)scol[j] * 128 + t]);
    float o = acc + b2v[t];
    o = o > 0.f ? o : __expf(o) - 1.0f;
    hfin[(size_t)n * 128 + t] = o;
}

// ---- parallel mean-pool partials: grid GG*SPLIT, atomicAdd into pooled
__global__ __launch_bounds__(128) void k_pool(
    const int* __restrict__ gstart, const float* __restrict__ hfin,
    float* __restrict__ pooled) {
    int g = blockIdx.x / SPLIT, i = blockIdx.x % SPLIT, t = threadIdx.x;
    int s0 = gstart[g], s1 = gstart[g + 1];
    int len = s1 - s0;
    int chunk = (len + SPLIT - 1) / SPLIT;
    int a = s0 + i * chunk;
    int b = min(a + chunk, s1);
    if (a >= b) return;
    float acc = 0.f;
    for (int n = a; n < b; n++) acc += hfin[(size_t)n * 128 + t];
    atomicAdd(&pooled[g * 128 + t], acc);
}

// ---- graph MLP + classifier (pooled already summed)
__global__ __launch_bounds__(128) void k_head(
    const int* __restrict__ gstart, const float* __restrict__ pooled,
    const float* __restrict__ gfeat,
    const float* __restrict__ Wg1, const float* __restrict__ bg1,
    const float* __restrict__ Wg2, const float* __restrict__ bg2,
    const float* __restrict__ Wc1, const float* __restrict__ bc1,
    const float* __restrict__ Wc2, const float* __restrict__ bc2,
    float* __restrict__ out) {
    __shared__ float z[160];
    __shared__ float hg[32];
    __shared__ float c1b[128];
    int g = blockIdx.x, t = threadIdx.x;
    float cntf = (float)(gstart[g + 1] - gstart[g]);
    z[t] = pooled[g * 128 + t] / fmaxf(cntf, 1.0f);
    if (t < 32) {
        float a = bg1[t];
        for (int i = 0; i < 10; i++) a += gfeat[g * 10 + i] * Wg1[i * 32 + t];
        hg[t] = fmaxf(a, 0.f);
    }
    __syncthreads();
    if (t < 32) {
        float a = bg2[t];
        for (int i = 0; i < 32; i++) a += hg[i] * Wg2[i * 32 + t];
        z[128 + t] = a;
    }
    __syncthreads();
    float a = bc1[t];
    for (int i = 0; i < 160; i++) a += z[i] * Wc1[i * 128 + t];
    c1b[t] = fmaxf(a, 0.f);
    __syncthreads();
    if (t < 6) {
        float o = bc2[t];
        for (int i = 0; i < 128; i++) o += c1b[i] * Wc2[i * 6 + t];
        out[g * 6 + t] = o;
    }
}

extern "C" void kernel_launch(void* const* d_in, const int* in_sizes, int n_in,
                              void* d_out, int out_size, void* d_ws, size_t ws_size,
                              hipStream_t stream) {
    const float* x     = (const float*)d_in[0];
    const int*   ei    = (const int*)d_in[1];
    const int*   batch = (const int*)d_in[2];
    const float* gfeat = (const float*)d_in[3];
    const float* W1    = (const float*)d_in[4];
    const float* as1   = (const float*)d_in[5];
    const float* ad1   = (const float*)d_in[6];
    const float* b1    = (const float*)d_in[7];
    const float* W2    = (const float*)d_in[8];
    const float* as2   = (const float*)d_in[9];
    const float* ad2   = (const float*)d_in[10];
    const float* b2    = (const float*)d_in[11];
    const float* Wg1   = (const float*)d_in[12];
    const float* bg1   = (const float*)d_in[13];
    const float* Wg2   = (const float*)d_in[14];
    const float* bg2   = (const float*)d_in[15];
    const float* Wc1   = (const float*)d_in[16];
    const float* bc1   = (const float*)d_in[17];
    const float* Wc2   = (const float*)d_in[18];
    const float* bc2   = (const float*)d_in[19];
    float* out = (float*)d_out;

    // workspace layout (256B aligned slices); total ~162 MB
    size_t off = 0;
    char* base = (char*)d_ws;
    auto take = [&](size_t nbytes) -> char* {
        char* p = base + off;
        off = (off + nbytes + 255) & ~(size_t)255;
        return p;
    };
    u16*   h1     = (u16*)take((size_t)NN * 512 * 2);
    u16*   h2pre  = (u16*)take((size_t)NN * 512 * 2);
    u16*   hL2    = (u16*)take((size_t)NN * 128 * 2);
    float* hfin   = (float*)take((size_t)NN * 128 * 4);
    float* a_src1 = (float*)take((size_t)NN * 4 * 4);
    float* a_dst1 = (float*)take((size_t)NN * 4 * 4);
    float* a_src2 = (float*)take((size_t)NN * 4);
    float* a_dst2 = (float*)take((size_t)NN * 4);
    int*   deg    = (int*)take((size_t)NN * 4);
    int*   col    = (int*)take((size_t)NN * CAP * 4);
    float* pooled = (float*)take(GG * 128 * 4);
    int*   gstart = (int*)take((GG + 1) * 4);
    u16*   W2p    = (u16*)take((size_t)512 * 128 * 2);
    (void)ws_size; (void)in_sizes; (void)n_in; (void)out_size;

    hipMemsetAsync(pooled, 0, GG * 128 * 4, stream);
    k_init<<<(NN + 255) / 256, 256, 0, stream>>>(deg, col);
    k_gstart<<<1, 128, 0, stream>>>(batch, gstart);
    k_cvtW2<<<256, 256, 0, stream>>>(W2, W2p);
    k_edges<<<(EE + 255) / 256, 256, 0, stream>>>(ei, deg, col);
    k_gemm1<<<NN, 256, 0, stream>>>(x, W1, as1, ad1, h1, a_src1, a_dst1);
    k_agg1<<<NN, 256, 0, stream>>>(deg, col, a_src1, a_dst1, h1, b1, h2pre);
    k_gemm2<<<(NN + 63) / 64, 256, 0, stream>>>(h2pre, W2p, as2, ad2, hL2, a_src2, a_dst2);
    k_agg2<<<NN, 128, 0, stream>>>(deg, col, a_src2, a_dst2, hL2, b2, hfin);
    k_pool<<<GG * SPLIT, 128, 0, stream>>>(gstart, hfin, pooled);
    k_head<<<GG, 128, 0, stream>>>(gstart, pooled, gfeat, Wg1, bg1, Wg2, bg2,
                                   Wc1, bc1, Wc2, bc2, out);
}

// Round 5
// 368.285 us; speedup vs baseline: 2.6721x; 1.2021x over previous
//
#include <hip/hip_runtime.h>
#include <hip/hip_bf16.h>

#define NN 50000
#define EE 400000
#define GG 64
#define CAP 96
#define SPLIT 16

typedef unsigned short u16;
typedef __attribute__((ext_vector_type(8))) short bf16x8;
typedef __attribute__((ext_vector_type(4))) float f32x4;

// bf16 <-> f32 used ONLY for internal workspace tensors.
__device__ __forceinline__ float b2f(u16 u) {
    unsigned int x = ((unsigned int)u) << 16;
    return __uint_as_float(x);
}
__device__ __forceinline__ u16 f2b(float f) {
    unsigned int x = __float_as_uint(f);
    unsigned int r = x + 0x7fffu + ((x >> 16) & 1u);
    return (u16)(r >> 16);
}
__device__ __forceinline__ float wred_sum(float v) {
    #pragma unroll
    for (int o = 32; o; o >>= 1) v += __shfl_xor(v, o, 64);
    return v;
}
__device__ __forceinline__ float wred_max(float v) {
    #pragma unroll
    for (int o = 32; o; o >>= 1) v = fmaxf(v, __shfl_xor(v, o, 64));
    return v;
}

// ---- init: degree=1 (self loop), seed CSR bucket with self loop. NO atomics.
__global__ void k_init(int* __restrict__ deg, int* __restrict__ col) {
    int n = blockIdx.x * 256 + threadIdx.x;
    if (n < NN) {
        deg[n] = 1;
        col[(size_t)n * CAP] = n;
    }
}

// ---- graph segment starts via binary search over sorted batch (no atomics)
__global__ void k_gstart(const int* __restrict__ batch, int* __restrict__ gstart) {
    int g = threadIdx.x;
    if (g <= GG) {
        int lo = 0, hi = NN;
        while (lo < hi) {
            int mid = (lo + hi) >> 1;
            if (batch[mid] < g) lo = mid + 1; else hi = mid;
        }
        gstart[g] = lo;
    }
}

// ---- bucket-append edges by dst
__global__ void k_edges(const int* __restrict__ ei, int* __restrict__ deg,
                        int* __restrict__ col) {
    int e = blockIdx.x * 256 + threadIdx.x;
    if (e < EE) {
        int s = ei[e];
        int d = ei[EE + e];
        int slot = atomicAdd(&deg[d], 1);
        if (slot < CAP) col[(size_t)d * CAP + slot] = s;
    }
}

// ---- prep W1: compute asW[k][h] = W1[:,head]@att (fp32) and pack
// [W1 | asW] into bf16 MFMA B-frag order, K padded 16->32 with zeros.
// 33 tiles: tile t covers cols t*16..t*16+15 (512..527 = 8 score cols + pad).
// W1p[((t*64+l)*8)+j] = B[k=quad*8+j][n=t*16+m]
__global__ void k_prepW1(const float* __restrict__ W1,
                         const float* __restrict__ as1, const float* __restrict__ ad1,
                         u16* __restrict__ W1p) {
    __shared__ float asw[16][8];
    int t = threadIdx.x;
    if (t < 128) {
        int k = t >> 3, h = t & 7;
        int hd = h & 3;
        const float* att = (h >= 4) ? ad1 : as1;
        float s = 0.f;
        for (int c = 0; c < 128; c++) s += W1[k * 512 + hd * 128 + c] * att[hd * 128 + c];
        asw[k][h] = s;
    }
    __syncthreads();
    for (int idx = t; idx < 33 * 64 * 8; idx += 256) {
        int j = idx & 7, l = (idx >> 3) & 63, tt = idx >> 9;
        int quad = l >> 4, m = l & 15;
        int k = quad * 8 + j;
        float v = 0.f;
        if (k < 16) {
            if (tt < 32) v = W1[k * 512 + tt * 16 + m];
            else if (m < 8) v = asw[k][m];
        }
        W1p[idx] = f2b(v);
    }
}

// ---- pack W2 (fp32 [512][128]) into bf16 MFMA B-fragment order.
__global__ void k_cvtW2(const float* __restrict__ W2, u16* __restrict__ W2p) {
    int idx = blockIdx.x * 256 + threadIdx.x;  // 65536 total
    int j = idx & 7;
    int l = (idx >> 3) & 63;
    int ct = idx >> 9;
    int c = ct >> 3, tt = ct & 7;
    int k = c * 32 + (l >> 4) * 8 + j;
    int n = tt * 16 + (l & 15);
    W2p[idx] = f2b(W2[k * 128 + n]);
}

// ---- layer1 linear via MFMA: [h1 | a_src1 | a_dst1] = x @ [W1 | asW]
// Block = 4 waves; wave computes rows [row0,row0+16) x 528 cols (33 tiles).
// A: lane l loads x[row0+(l&15)][quad*8..+7] fp32->bf16 (quads 2,3 = K-pad zeros).
// C/D: col=lane&15, row=quad*4+reg.
__global__ __launch_bounds__(256) void k_gemm1(
    const float* __restrict__ x, const u16* __restrict__ W1p,
    u16* __restrict__ h1, float* __restrict__ a_src1, float* __restrict__ a_dst1) {
    int tid = threadIdx.x;
    int wave = tid >> 6, l = tid & 63;
    int quad = l >> 4, m = l & 15;
    int row0 = blockIdx.x * 64 + wave * 16;
    int arow = row0 + m;
    int arow_c = arow < NN ? arow : (NN - 1);
    bf16x8 af;
    if (quad < 2) {
        const float* xp = x + arow_c * 16 + quad * 8;
        float4 x0 = *(const float4*)(xp);
        float4 x1 = *(const float4*)(xp + 4);
        u16 tmp[8] = {f2b(x0.x), f2b(x0.y), f2b(x0.z), f2b(x0.w),
                      f2b(x1.x), f2b(x1.y), f2b(x1.z), f2b(x1.w)};
        af = *(bf16x8*)tmp;
    } else {
        af = (bf16x8){0, 0, 0, 0, 0, 0, 0, 0};
    }
    const u16* bp = W1p + l * 8;
    f32x4 acc[33];
    #pragma unroll
    for (int tt = 0; tt < 33; tt++) acc[tt] = (f32x4){0.f, 0.f, 0.f, 0.f};
    #pragma unroll
    for (int tt = 0; tt < 33; tt++) {
        bf16x8 bf = *(const bf16x8*)(bp + (size_t)tt * 512);
        acc[tt] = __builtin_amdgcn_mfma_f32_16x16x32_bf16(af, bf, acc[tt], 0, 0, 0);
    }
    #pragma unroll
    for (int r = 0; r < 4; r++) {
        int row = row0 + quad * 4 + r;
        if (row >= NN) continue;
        #pragma unroll
        for (int tt = 0; tt < 32; tt++)
            h1[(size_t)row * 512 + tt * 16 + m] = f2b(acc[tt][r]);
        float v = acc[32][r];
        if (m < 4) a_src1[row * 4 + m] = v;
        else if (m < 8) a_dst1[row * 4 + (m - 4)] = v;
    }
}

// ---- layer1 attention softmax + aggregation + bias + ELU -> h2pre (bf16)
__global__ __launch_bounds__(256) void k_agg1(
    const int* __restrict__ deg, const int* __restrict__ col,
    const float* __restrict__ a_src1, const float* __restrict__ a_dst1,
    const u16* __restrict__ h1, const float* __restrict__ b1,
    u16* __restrict__ h2pre) {
    __shared__ float ew[CAP * 4];
    __shared__ int scol[CAP];
    int n = blockIdx.x, t = threadIdx.x;
    int dg = min(deg[n], CAP);
    float ad0 = a_dst1[n * 4 + 0], ad1v = a_dst1[n * 4 + 1];
    float ad2v = a_dst1[n * 4 + 2], ad3v = a_dst1[n * 4 + 3];
    for (int j = t; j < dg; j += 256) {
        int s = col[(size_t)n * CAP + j];
        scol[j] = s;
        float4 av = *(const float4*)(a_src1 + s * 4);
        float v0 = av.x + ad0; ew[j * 4 + 0] = v0 > 0.f ? v0 : 0.2f * v0;
        float v1 = av.y + ad1v; ew[j * 4 + 1] = v1 > 0.f ? v1 : 0.2f * v1;
        float v2 = av.z + ad2v; ew[j * 4 + 2] = v2 > 0.f ? v2 : 0.2f * v2;
        float v3 = av.w + ad3v; ew[j * 4 + 3] = v3 > 0.f ? v3 : 0.2f * v3;
    }
    __syncthreads();
    int w = t >> 6, l = t & 63;
    float mx = -1e30f;
    for (int j = l; j < dg; j += 64) mx = fmaxf(mx, ew[j * 4 + w]);
    mx = wred_max(mx);
    float sm = 0.f;
    for (int j = l; j < dg; j += 64) {
        float ex = __expf(ew[j * 4 + w] - mx);
        ew[j * 4 + w] = ex;
        sm += ex;
    }
    sm = wred_sum(sm);
    float inv = 1.0f / sm;
    for (int j = l; j < dg; j += 64) ew[j * 4 + w] *= inv;
    __syncthreads();
    float acc0 = 0.f, acc1 = 0.f;
    int hh = t >> 6;
    for (int j = 0; j < dg; j++) {
        int s = scol[j];
        float al = ew[j * 4 + hh];
        ushort2 u = *(const ushort2*)(h1 + (size_t)s * 512 + 2 * t);
        acc0 += al * b2f(u.x);
        acc1 += al * b2f(u.y);
    }
    float o0 = acc0 + b1[2 * t];     o0 = o0 > 0.f ? o0 : __expf(o0) - 1.0f;
    float o1 = acc1 + b1[2 * t + 1]; o1 = o1 > 0.f ? o1 : __expf(o1) - 1.0f;
    ushort2 ov; ov.x = f2b(o0); ov.y = f2b(o1);
    *(ushort2*)(h2pre + (size_t)n * 512 + 2 * t) = ov;
}

// ---- layer2 linear via MFMA: hL2 = h2pre@W2 (bf16), fused a_src2/a_dst2.
__global__ __launch_bounds__(256) void k_gemm2(
    const u16* __restrict__ h2pre, const u16* __restrict__ W2p,
    const float* __restrict__ as2, const float* __restrict__ ad2,
    u16* __restrict__ hL2, float* __restrict__ a_src2, float* __restrict__ a_dst2) {
    int t = threadIdx.x;
    int wave = t >> 6, l = t & 63;
    int quad = l >> 4, m = l & 15;
    int row0 = blockIdx.x * 64 + wave * 16;
    int arow = row0 + m;
    int arow_c = arow < NN ? arow : (NN - 1);
    const u16* aptr = h2pre + (size_t)arow_c * 512 + quad * 8;
    const u16* bptr = W2p + l * 8;
    f32x4 acc[8];
    #pragma unroll
    for (int tt = 0; tt < 8; tt++) acc[tt] = (f32x4){0.f, 0.f, 0.f, 0.f};
    for (int c = 0; c < 16; c++) {
        bf16x8 af = *(const bf16x8*)(aptr + c * 32);
        #pragma unroll
        for (int tt = 0; tt < 8; tt++) {
            bf16x8 bf = *(const bf16x8*)(bptr + (size_t)(c * 8 + tt) * 512);
            acc[tt] = __builtin_amdgcn_mfma_f32_16x16x32_bf16(af, bf, acc[tt], 0, 0, 0);
        }
    }
    float asv[8], adv[8];
    #pragma unroll
    for (int tt = 0; tt < 8; tt++) {
        int colc = tt * 16 + m;
        asv[tt] = as2[colc];
        adv[tt] = ad2[colc];
    }
    #pragma unroll
    for (int r = 0; r < 4; r++) {
        int row = row0 + quad * 4 + r;
        bool ok = row < NN;
        float rs = 0.f, rd = 0.f;
        #pragma unroll
        for (int tt = 0; tt < 8; tt++) {
            float v = acc[tt][r];
            if (ok) hL2[(size_t)row * 128 + tt * 16 + m] = f2b(v);
            rs += v * asv[tt];
            rd += v * adv[tt];
        }
        #pragma unroll
        for (int o = 1; o < 16; o <<= 1) {
            rs += __shfl_xor(rs, o, 64);
            rd += __shfl_xor(rd, o, 64);
        }
        if (ok && m == 0) { a_src2[row] = rs; a_dst2[row] = rd; }
    }
}

// ---- layer2 attention softmax + aggregation + bias + ELU -> h_final (fp32)
__global__ __launch_bounds__(128) void k_agg2(
    const int* __restrict__ deg, const int* __restrict__ col,
    const float* __restrict__ a_src2, const float* __restrict__ a_dst2,
    const u16* __restrict__ hL2, const float* __restrict__ b2v,
    float* __restrict__ hfin) {
    __shared__ float ew[CAP];
    __shared__ int scol[CAP];
    int n = blockIdx.x, t = threadIdx.x;
    int dg = min(deg[n], CAP);
    float ad = a_dst2[n];
    for (int j = t; j < dg; j += 128) {
        int s = col[(size_t)n * CAP + j];
        scol[j] = s;
        float v = a_src2[s] + ad;
        ew[j] = v > 0.f ? v : 0.2f * v;
    }
    __syncthreads();
    if (t < 64) {
        float mx = -1e30f;
        for (int j = t; j < dg; j += 64) mx = fmaxf(mx, ew[j]);
        mx = wred_max(mx);
        float sm = 0.f;
        for (int j = t; j < dg; j += 64) {
            float ex = __expf(ew[j] - mx);
            ew[j] = ex;
            sm += ex;
        }
        sm = wred_sum(sm);
        float inv = 1.0f / sm;
        for (int j = t; j < dg; j += 64) ew[j] *= inv;
    }
    __syncthreads();
    float acc = 0.f;
    for (int j = 0; j < dg; j++) acc += ew[j] * b2f(hL2[(size_t)scol[j] * 128 + t]);
    float o = acc + b2v[t];
    o = o > 0.f ? o : __expf(o) - 1.0f;
    hfin[(size_t)n * 128 + t] = o;
}

// ---- parallel mean-pool partials: grid GG*SPLIT, atomicAdd into pooled
__global__ __launch_bounds__(128) void k_pool(
    const int* __restrict__ gstart, const float* __restrict__ hfin,
    float* __restrict__ pooled) {
    int g = blockIdx.x / SPLIT, i = blockIdx.x % SPLIT, t = threadIdx.x;
    int s0 = gstart[g], s1 = gstart[g + 1];
    int len = s1 - s0;
    int chunk = (len + SPLIT - 1) / SPLIT;
    int a = s0 + i * chunk;
    int b = min(a + chunk, s1);
    if (a >= b) return;
    float acc = 0.f;
    for (int n = a; n < b; n++) acc += hfin[(size_t)n * 128 + t];
    atomicAdd(&pooled[g * 128 + t], acc);
}

// ---- graph MLP + classifier (pooled already summed)
__global__ __launch_bounds__(128) void k_head(
    const int* __restrict__ gstart, const float* __restrict__ pooled,
    const float* __restrict__ gfeat,
    const float* __restrict__ Wg1, const float* __restrict__ bg1,
    const float* __restrict__ Wg2, const float* __restrict__ bg2,
    const float* __restrict__ Wc1, const float* __restrict__ bc1,
    const float* __restrict__ Wc2, const float* __restrict__ bc2,
    float* __restrict__ out) {
    __shared__ float z[160];
    __shared__ float hg[32];
    __shared__ float c1b[128];
    int g = blockIdx.x, t = threadIdx.x;
    float cntf = (float)(gstart[g + 1] - gstart[g]);
    z[t] = pooled[g * 128 + t] / fmaxf(cntf, 1.0f);
    if (t < 32) {
        float a = bg1[t];
        for (int i = 0; i < 10; i++) a += gfeat[g * 10 + i] * Wg1[i * 32 + t];
        hg[t] = fmaxf(a, 0.f);
    }
    __syncthreads();
    if (t < 32) {
        float a = bg2[t];
        for (int i = 0; i < 32; i++) a += hg[i] * Wg2[i * 32 + t];
        z[128 + t] = a;
    }
    __syncthreads();
    float a = bc1[t];
    for (int i = 0; i < 160; i++) a += z[i] * Wc1[i * 128 + t];
    c1b[t] = fmaxf(a, 0.f);
    __syncthreads();
    if (t < 6) {
        float o = bc2[t];
        for (int i = 0; i < 128; i++) o += c1b[i] * Wc2[i * 6 + t];
        out[g * 6 + t] = o;
    }
}

extern "C" void kernel_launch(void* const* d_in, const int* in_sizes, int n_in,
                              void* d_out, int out_size, void* d_ws, size_t ws_size,
                              hipStream_t stream) {
    const float* x     = (const float*)d_in[0];
    const int*   ei    = (const int*)d_in[1];
    const int*   batch = (const int*)d_in[2];
    const float* gfeat = (const float*)d_in[3];
    const float* W1    = (const float*)d_in[4];
    const float* as1   = (const float*)d_in[5];
    const float* ad1   = (const float*)d_in[6];
    const float* b1    = (const float*)d_in[7];
    const float* W2    = (const float*)d_in[8];
    const float* as2   = (const float*)d_in[9];
    const float* ad2   = (const float*)d_in[10];
    const float* b2    = (const float*)d_in[11];
    const float* Wg1   = (const float*)d_in[12];
    const float* bg1   = (const float*)d_in[13];
    const float* Wg2   = (const float*)d_in[14];
    const float* bg2   = (const float*)d_in[15];
    const float* Wc1   = (const float*)d_in[16];
    const float* bc1   = (const float*)d_in[17];
    const float* Wc2   = (const float*)d_in[18];
    const float* bc2   = (const float*)d_in[19];
    float* out = (float*)d_out;

    size_t off = 0;
    char* base = (char*)d_ws;
    auto take = [&](size_t nbytes) -> char* {
        char* p = base + off;
        off = (off + nbytes + 255) & ~(size_t)255;
        return p;
    };
    u16*   h1     = (u16*)take((size_t)NN * 512 * 2);
    u16*   h2pre  = (u16*)take((size_t)NN * 512 * 2);
    u16*   hL2    = (u16*)take((size_t)NN * 128 * 2);
    float* hfin   = (float*)take((size_t)NN * 128 * 4);
    float* a_src1 = (float*)take((size_t)NN * 4 * 4);
    float* a_dst1 = (float*)take((size_t)NN * 4 * 4);
    float* a_src2 = (float*)take((size_t)NN * 4);
    float* a_dst2 = (float*)take((size_t)NN * 4);
    int*   deg    = (int*)take((size_t)NN * 4);
    int*   col    = (int*)take((size_t)NN * CAP * 4);
    float* pooled = (float*)take(GG * 128 * 4);
    int*   gstart = (int*)take((GG + 1) * 4);
    u16*   W2p    = (u16*)take((size_t)512 * 128 * 2);
    u16*   W1p    = (u16*)take((size_t)33 * 64 * 8 * 2);
    (void)ws_size; (void)in_sizes; (void)n_in; (void)out_size;

    hipMemsetAsync(pooled, 0, GG * 128 * 4, stream);
    k_init<<<(NN + 255) / 256, 256, 0, stream>>>(deg, col);
    k_gstart<<<1, 128, 0, stream>>>(batch, gstart);
    k_prepW1<<<1, 256, 0, stream>>>(W1, as1, ad1, W1p);
    k_cvtW2<<<256, 256, 0, stream>>>(W2, W2p);
    k_edges<<<(EE + 255) / 256, 256, 0, stream>>>(ei, deg, col);
    k_gemm1<<<(NN + 63) / 64, 256, 0, stream>>>(x, W1p, h1, a_src1, a_dst1);
    k_agg1<<<NN, 256, 0, stream>>>(deg, col, a_src1, a_dst1, h1, b1, h2pre);
    k_gemm2<<<(NN + 63) / 64, 256, 0, stream>>>(h2pre, W2p, as2, ad2, hL2, a_src2, a_dst2);
    k_agg2<<<NN, 128, 0, stream>>>(deg, col, a_src2, a_dst2, hL2, b2, hfin);
    k_pool<<<GG * SPLIT, 128, 0, stream>>>(gstart, hfin, pooled);
    k_head<<<GG, 128, 0, stream>>>(gstart, pooled, gfeat, Wg1, bg1, Wg2, bg2,
                                   Wc1, bc1, Wc2, bc2, out);
}

// Round 6
// 329.668 us; speedup vs baseline: 2.9851x; 1.1171x over previous
//
#include <hip/hip_runtime.h>
#include <hip/hip_bf16.h>

#define NN 50000
#define EE 400000
#define GG 64
#define CAP 96
#define SPLIT 16

typedef unsigned short u16;
typedef __attribute__((ext_vector_type(8))) short bf16x8;
typedef __attribute__((ext_vector_type(4))) float f32x4;

// bf16 <-> f32 used ONLY for internal workspace tensors.
__device__ __forceinline__ float b2f(u16 u) {
    unsigned int x = ((unsigned int)u) << 16;
    return __uint_as_float(x);
}
__device__ __forceinline__ u16 f2b(float f) {
    unsigned int x = __float_as_uint(f);
    unsigned int r = x + 0x7fffu + ((x >> 16) & 1u);
    return (u16)(r >> 16);
}
__device__ __forceinline__ float wred_sum(float v) {
    #pragma unroll
    for (int o = 32; o; o >>= 1) v += __shfl_xor(v, o, 64);
    return v;
}
__device__ __forceinline__ float wred_max(float v) {
    #pragma unroll
    for (int o = 32; o; o >>= 1) v = fmaxf(v, __shfl_xor(v, o, 64));
    return v;
}
__device__ __forceinline__ float lrelu(float v) { return v > 0.f ? v : 0.2f * v; }

// ---- init: degree=1 (self loop), seed CSR bucket with self loop. NO atomics.
__global__ void k_init(int* __restrict__ deg, int* __restrict__ col) {
    int n = blockIdx.x * 256 + threadIdx.x;
    if (n < NN) {
        deg[n] = 1;
        col[(size_t)n * CAP] = n;
    }
}

// ---- graph segment starts via binary search over sorted batch (no atomics)
__global__ void k_gstart(const int* __restrict__ batch, int* __restrict__ gstart) {
    int g = threadIdx.x;
    if (g <= GG) {
        int lo = 0, hi = NN;
        while (lo < hi) {
            int mid = (lo + hi) >> 1;
            if (batch[mid] < g) lo = mid + 1; else hi = mid;
        }
        gstart[g] = lo;
    }
}

// ---- bucket-append edges by dst
__global__ void k_edges(const int* __restrict__ ei, int* __restrict__ deg,
                        int* __restrict__ col) {
    int e = blockIdx.x * 256 + threadIdx.x;
    if (e < EE) {
        int s = ei[e];
        int d = ei[EE + e];
        int slot = atomicAdd(&deg[d], 1);
        if (slot < CAP) col[(size_t)d * CAP + slot] = s;
    }
}

// ---- prep W1: compute asW[k][h] = W1[:,head]@att (fp32) and pack
// [W1 | asW] into bf16 MFMA B-frag order, K padded 16->32 with zeros.
__global__ void k_prepW1(const float* __restrict__ W1,
                         const float* __restrict__ as1, const float* __restrict__ ad1,
                         u16* __restrict__ W1p) {
    __shared__ float asw[16][8];
    int t = threadIdx.x;
    if (t < 128) {
        int k = t >> 3, h = t & 7;
        int hd = h & 3;
        const float* att = (h >= 4) ? ad1 : as1;
        float s = 0.f;
        for (int c = 0; c < 128; c++) s += W1[k * 512 + hd * 128 + c] * att[hd * 128 + c];
        asw[k][h] = s;
    }
    __syncthreads();
    for (int idx = t; idx < 33 * 64 * 8; idx += 256) {
        int j = idx & 7, l = (idx >> 3) & 63, tt = idx >> 9;
        int quad = l >> 4, m = l & 15;
        int k = quad * 8 + j;
        float v = 0.f;
        if (k < 16) {
            if (tt < 32) v = W1[k * 512 + tt * 16 + m];
            else if (m < 8) v = asw[k][m];
        }
        W1p[idx] = f2b(v);
    }
}

// ---- pack W2 (fp32 [512][128]) into bf16 MFMA B-fragment order.
__global__ void k_cvtW2(const float* __restrict__ W2, u16* __restrict__ W2p) {
    int idx = blockIdx.x * 256 + threadIdx.x;  // 65536 total
    int j = idx & 7;
    int l = (idx >> 3) & 63;
    int ct = idx >> 9;
    int c = ct >> 3, tt = ct & 7;
    int k = c * 32 + (l >> 4) * 8 + j;
    int n = tt * 16 + (l & 15);
    W2p[idx] = f2b(W2[k * 128 + n]);
}

// ---- layer1 linear via MFMA: [h1 | a_src1 | a_dst1] = x @ [W1 | asW]
__global__ __launch_bounds__(256) void k_gemm1(
    const float* __restrict__ x, const u16* __restrict__ W1p,
    u16* __restrict__ h1, float* __restrict__ a_src1, float* __restrict__ a_dst1) {
    int tid = threadIdx.x;
    int wave = tid >> 6, l = tid & 63;
    int quad = l >> 4, m = l & 15;
    int row0 = blockIdx.x * 64 + wave * 16;
    int arow = row0 + m;
    int arow_c = arow < NN ? arow : (NN - 1);
    bf16x8 af;
    if (quad < 2) {
        const float* xp = x + arow_c * 16 + quad * 8;
        float4 x0 = *(const float4*)(xp);
        float4 x1 = *(const float4*)(xp + 4);
        u16 tmp[8] = {f2b(x0.x), f2b(x0.y), f2b(x0.z), f2b(x0.w),
                      f2b(x1.x), f2b(x1.y), f2b(x1.z), f2b(x1.w)};
        af = *(bf16x8*)tmp;
    } else {
        af = (bf16x8){0, 0, 0, 0, 0, 0, 0, 0};
    }
    const u16* bp = W1p + l * 8;
    f32x4 acc[33];
    #pragma unroll
    for (int tt = 0; tt < 33; tt++) acc[tt] = (f32x4){0.f, 0.f, 0.f, 0.f};
    #pragma unroll
    for (int tt = 0; tt < 33; tt++) {
        bf16x8 bf = *(const bf16x8*)(bp + (size_t)tt * 512);
        acc[tt] = __builtin_amdgcn_mfma_f32_16x16x32_bf16(af, bf, acc[tt], 0, 0, 0);
    }
    #pragma unroll
    for (int r = 0; r < 4; r++) {
        int row = row0 + quad * 4 + r;
        if (row >= NN) continue;
        #pragma unroll
        for (int tt = 0; tt < 32; tt++)
            h1[(size_t)row * 512 + tt * 16 + m] = f2b(acc[tt][r]);
        float v = acc[32][r];
        if (m < 4) a_src1[row * 4 + m] = v;
        else if (m < 8) a_dst1[row * 4 + (m - 4)] = v;
    }
}

// ---- layer1 attention: WAVE-PER-NODE, register softmax, no LDS/barriers.
// Edge j lives in lane j&63, slot j>>6 (CAP=96 <= 128). Lane l aggregates
// channels l*8..l*8+7 (all within head l>>4).
__global__ __launch_bounds__(256) void k_agg1(
    const int* __restrict__ deg, const int* __restrict__ col,
    const float* __restrict__ a_src1, const float* __restrict__ a_dst1,
    const u16* __restrict__ h1, const float* __restrict__ b1,
    u16* __restrict__ h2pre) {
    int t = threadIdx.x;
    int wave = t >> 6, l = t & 63;
    int n = blockIdx.x * 4 + wave;
    if (n >= NN) return;
    int dg = min(deg[n], CAP);
    int s0 = (l < dg) ? col[(size_t)n * CAP + l] : 0;
    int s1 = (l + 64 < dg) ? col[(size_t)n * CAP + l + 64] : 0;
    float4 ad = *(const float4*)(a_dst1 + n * 4);
    float4 e0, e1;
    {
        float4 as = *(const float4*)(a_src1 + (size_t)s0 * 4);
        e0.x = lrelu(as.x + ad.x); e0.y = lrelu(as.y + ad.y);
        e0.z = lrelu(as.z + ad.z); e0.w = lrelu(as.w + ad.w);
        if (l >= dg) e0 = (float4){-1e30f, -1e30f, -1e30f, -1e30f};
    }
    {
        float4 as = *(const float4*)(a_src1 + (size_t)s1 * 4);
        e1.x = lrelu(as.x + ad.x); e1.y = lrelu(as.y + ad.y);
        e1.z = lrelu(as.z + ad.z); e1.w = lrelu(as.w + ad.w);
        if (l + 64 >= dg) e1 = (float4){-1e30f, -1e30f, -1e30f, -1e30f};
    }
    float4 mx;
    mx.x = wred_max(fmaxf(e0.x, e1.x));
    mx.y = wred_max(fmaxf(e0.y, e1.y));
    mx.z = wred_max(fmaxf(e0.z, e1.z));
    mx.w = wred_max(fmaxf(e0.w, e1.w));
    e0.x = __expf(e0.x - mx.x); e0.y = __expf(e0.y - mx.y);
    e0.z = __expf(e0.z - mx.z); e0.w = __expf(e0.w - mx.w);
    e1.x = __expf(e1.x - mx.x); e1.y = __expf(e1.y - mx.y);
    e1.z = __expf(e1.z - mx.z); e1.w = __expf(e1.w - mx.w);
    float4 inv;
    inv.x = 1.0f / wred_sum(e0.x + e1.x);
    inv.y = 1.0f / wred_sum(e0.y + e1.y);
    inv.z = 1.0f / wred_sum(e0.z + e1.z);
    inv.w = 1.0f / wred_sum(e0.w + e1.w);
    e0.x *= inv.x; e0.y *= inv.y; e0.z *= inv.z; e0.w *= inv.w;
    e1.x *= inv.x; e1.y *= inv.y; e1.z *= inv.z; e1.w *= inv.w;
    int h = l >> 4;
    float acc[8] = {0.f, 0.f, 0.f, 0.f, 0.f, 0.f, 0.f, 0.f};
    const u16* hb = h1 + l * 8;
    for (int j = 0; j < dg; j++) {
        int sj; float ax, ay, az, aw;
        if (j < 64) {
            sj = __shfl(s0, j);
            ax = __shfl(e0.x, j); ay = __shfl(e0.y, j);
            az = __shfl(e0.z, j); aw = __shfl(e0.w, j);
        } else {
            sj = __shfl(s1, j - 64);
            ax = __shfl(e1.x, j - 64); ay = __shfl(e1.y, j - 64);
            az = __shfl(e1.z, j - 64); aw = __shfl(e1.w, j - 64);
        }
        float al = h == 0 ? ax : (h == 1 ? ay : (h == 2 ? az : aw));
        bf16x8 hv = *(const bf16x8*)(hb + (size_t)sj * 512);
        #pragma unroll
        for (int k = 0; k < 8; k++) acc[k] += al * b2f((u16)hv[k]);
    }
    float4 bA = *(const float4*)(b1 + l * 8);
    float4 bB = *(const float4*)(b1 + l * 8 + 4);
    float bb[8] = {bA.x, bA.y, bA.z, bA.w, bB.x, bB.y, bB.z, bB.w};
    u16 ov[8];
    #pragma unroll
    for (int k = 0; k < 8; k++) {
        float v = acc[k] + bb[k];
        v = v > 0.f ? v : __expf(v) - 1.0f;
        ov[k] = f2b(v);
    }
    *(bf16x8*)(h2pre + (size_t)n * 512 + l * 8) = *(bf16x8*)ov;
}

// ---- layer2 linear via MFMA: hL2 = h2pre@W2 (bf16), fused a_src2/a_dst2.
__global__ __launch_bounds__(256) void k_gemm2(
    const u16* __restrict__ h2pre, const u16* __restrict__ W2p,
    const float* __restrict__ as2, const float* __restrict__ ad2,
    u16* __restrict__ hL2, float* __restrict__ a_src2, float* __restrict__ a_dst2) {
    int t = threadIdx.x;
    int wave = t >> 6, l = t & 63;
    int quad = l >> 4, m = l & 15;
    int row0 = blockIdx.x * 64 + wave * 16;
    int arow = row0 + m;
    int arow_c = arow < NN ? arow : (NN - 1);
    const u16* aptr = h2pre + (size_t)arow_c * 512 + quad * 8;
    const u16* bptr = W2p + l * 8;
    f32x4 acc[8];
    #pragma unroll
    for (int tt = 0; tt < 8; tt++) acc[tt] = (f32x4){0.f, 0.f, 0.f, 0.f};
    for (int c = 0; c < 16; c++) {
        bf16x8 af = *(const bf16x8*)(aptr + c * 32);
        #pragma unroll
        for (int tt = 0; tt < 8; tt++) {
            bf16x8 bf = *(const bf16x8*)(bptr + (size_t)(c * 8 + tt) * 512);
            acc[tt] = __builtin_amdgcn_mfma_f32_16x16x32_bf16(af, bf, acc[tt], 0, 0, 0);
        }
    }
    float asv[8], adv[8];
    #pragma unroll
    for (int tt = 0; tt < 8; tt++) {
        int colc = tt * 16 + m;
        asv[tt] = as2[colc];
        adv[tt] = ad2[colc];
    }
    #pragma unroll
    for (int r = 0; r < 4; r++) {
        int row = row0 + quad * 4 + r;
        bool ok = row < NN;
        float rs = 0.f, rd = 0.f;
        #pragma unroll
        for (int tt = 0; tt < 8; tt++) {
            float v = acc[tt][r];
            if (ok) hL2[(size_t)row * 128 + tt * 16 + m] = f2b(v);
            rs += v * asv[tt];
            rd += v * adv[tt];
        }
        #pragma unroll
        for (int o = 1; o < 16; o <<= 1) {
            rs += __shfl_xor(rs, o, 64);
            rd += __shfl_xor(rd, o, 64);
        }
        if (ok && m == 0) { a_src2[row] = rs; a_dst2[row] = rd; }
    }
}

// ---- layer2 attention: WAVE-PER-NODE, register softmax, no LDS/barriers.
// Lane l aggregates channels 2l, 2l+1.
__global__ __launch_bounds__(256) void k_agg2(
    const int* __restrict__ deg, const int* __restrict__ col,
    const float* __restrict__ a_src2, const float* __restrict__ a_dst2,
    const u16* __restrict__ hL2, const float* __restrict__ b2v,
    float* __restrict__ hfin) {
    int t = threadIdx.x;
    int wave = t >> 6, l = t & 63;
    int n = blockIdx.x * 4 + wave;
    if (n >= NN) return;
    int dg = min(deg[n], CAP);
    int s0 = (l < dg) ? col[(size_t)n * CAP + l] : 0;
    int s1 = (l + 64 < dg) ? col[(size_t)n * CAP + l + 64] : 0;
    float ad = a_dst2[n];
    float e0 = (l < dg) ? lrelu(a_src2[s0] + ad) : -1e30f;
    float e1 = (l + 64 < dg) ? lrelu(a_src2[s1] + ad) : -1e30f;
    float mx = wred_max(fmaxf(e0, e1));
    e0 = __expf(e0 - mx);
    e1 = __expf(e1 - mx);
    float inv = 1.0f / wred_sum(e0 + e1);
    e0 *= inv; e1 *= inv;
    float acc0 = 0.f, acc1 = 0.f;
    const u16* hb = hL2 + l * 2;
    for (int j = 0; j < dg; j++) {
        int sj; float al;
        if (j < 64) { sj = __shfl(s0, j); al = __shfl(e0, j); }
        else        { sj = __shfl(s1, j - 64); al = __shfl(e1, j - 64); }
        ushort2 u = *(const ushort2*)(hb + (size_t)sj * 128);
        acc0 += al * b2f(u.x);
        acc1 += al * b2f(u.y);
    }
    float o0 = acc0 + b2v[2 * l];     o0 = o0 > 0.f ? o0 : __expf(o0) - 1.0f;
    float o1 = acc1 + b2v[2 * l + 1]; o1 = o1 > 0.f ? o1 : __expf(o1) - 1.0f;
    float2 ov; ov.x = o0; ov.y = o1;
    *(float2*)(hfin + (size_t)n * 128 + 2 * l) = ov;
}

// ---- parallel mean-pool partials: grid GG*SPLIT, atomicAdd into pooled
__global__ __launch_bounds__(128) void k_pool(
    const int* __restrict__ gstart, const float* __restrict__ hfin,
    float* __restrict__ pooled) {
    int g = blockIdx.x / SPLIT, i = blockIdx.x % SPLIT, t = threadIdx.x;
    int s0 = gstart[g], s1 = gstart[g + 1];
    int len = s1 - s0;
    int chunk = (len + SPLIT - 1) / SPLIT;
    int a = s0 + i * chunk;
    int b = min(a + chunk, s1);
    if (a >= b) return;
    float acc = 0.f;
    for (int n = a; n < b; n++) acc += hfin[(size_t)n * 128 + t];
    atomicAdd(&pooled[g * 128 + t], acc);
}

// ---- graph MLP + classifier (pooled already summed)
__global__ __launch_bounds__(128) void k_head(
    const int* __restrict__ gstart, const float* __restrict__ pooled,
    const float* __restrict__ gfeat,
    const float* __restrict__ Wg1, const float* __restrict__ bg1,
    const float* __restrict__ Wg2, const float* __restrict__ bg2,
    const float* __restrict__ Wc1, const float* __restrict__ bc1,
    const float* __restrict__ Wc2, const float* __restrict__ bc2,
    float* __restrict__ out) {
    __shared__ float z[160];
    __shared__ float hg[32];
    __shared__ float c1b[128];
    int g = blockIdx.x, t = threadIdx.x;
    float cntf = (float)(gstart[g + 1] - gstart[g]);
    z[t] = pooled[g * 128 + t] / fmaxf(cntf, 1.0f);
    if (t < 32) {
        float a = bg1[t];
        for (int i = 0; i < 10; i++) a += gfeat[g * 10 + i] * Wg1[i * 32 + t];
        hg[t] = fmaxf(a, 0.f);
    }
    __syncthreads();
    if (t < 32) {
        float a = bg2[t];
        for (int i = 0; i < 32; i++) a += hg[i] * Wg2[i * 32 + t];
        z[128 + t] = a;
    }
    __syncthreads();
    float a = bc1[t];
    for (int i = 0; i < 160; i++) a += z[i] * Wc1[i * 128 + t];
    c1b[t] = fmaxf(a, 0.f);
    __syncthreads();
    if (t < 6) {
        float o = bc2[t];
        for (int i = 0; i < 128; i++) o += c1b[i] * Wc2[i * 6 + t];
        out[g * 6 + t] = o;
    }
}

extern "C" void kernel_launch(void* const* d_in, const int* in_sizes, int n_in,
                              void* d_out, int out_size, void* d_ws, size_t ws_size,
                              hipStream_t stream) {
    const float* x     = (const float*)d_in[0];
    const int*   ei    = (const int*)d_in[1];
    const int*   batch = (const int*)d_in[2];
    const float* gfeat = (const float*)d_in[3];
    const float* W1    = (const float*)d_in[4];
    const float* as1   = (const float*)d_in[5];
    const float* ad1   = (const float*)d_in[6];
    const float* b1    = (const float*)d_in[7];
    const float* W2    = (const float*)d_in[8];
    const float* as2   = (const float*)d_in[9];
    const float* ad2   = (const float*)d_in[10];
    const float* b2    = (const float*)d_in[11];
    const float* Wg1   = (const float*)d_in[12];
    const float* bg1   = (const float*)d_in[13];
    const float* Wg2   = (const float*)d_in[14];
    const float* bg2   = (const float*)d_in[15];
    const float* Wc1   = (const float*)d_in[16];
    const float* bc1   = (const float*)d_in[17];
    const float* Wc2   = (const float*)d_in[18];
    const float* bc2   = (const float*)d_in[19];
    float* out = (float*)d_out;

    size_t off = 0;
    char* base = (char*)d_ws;
    auto take = [&](size_t nbytes) -> char* {
        char* p = base + off;
        off = (off + nbytes + 255) & ~(size_t)255;
        return p;
    };
    u16*   h1     = (u16*)take((size_t)NN * 512 * 2);
    u16*   h2pre  = (u16*)take((size_t)NN * 512 * 2);
    u16*   hL2    = (u16*)take((size_t)NN * 128 * 2);
    float* hfin   = (float*)take((size_t)NN * 128 * 4);
    float* a_src1 = (float*)take((size_t)NN * 4 * 4);
    float* a_dst1 = (float*)take((size_t)NN * 4 * 4);
    float* a_src2 = (float*)take((size_t)NN * 4);
    float* a_dst2 = (float*)take((size_t)NN * 4);
    int*   deg    = (int*)take((size_t)NN * 4);
    int*   col    = (int*)take((size_t)NN * CAP * 4);
    float* pooled = (float*)take(GG * 128 * 4);
    int*   gstart = (int*)take((GG + 1) * 4);
    u16*   W2p    = (u16*)take((size_t)512 * 128 * 2);
    u16*   W1p    = (u16*)take((size_t)33 * 64 * 8 * 2);
    (void)ws_size; (void)in_sizes; (void)n_in; (void)out_size;

    hipMemsetAsync(pooled, 0, GG * 128 * 4, stream);
    k_init<<<(NN + 255) / 256, 256, 0, stream>>>(deg, col);
    k_gstart<<<1, 128, 0, stream>>>(batch, gstart);
    k_prepW1<<<1, 256, 0, stream>>>(W1, as1, ad1, W1p);
    k_cvtW2<<<256, 256, 0, stream>>>(W2, W2p);
    k_edges<<<(EE + 255) / 256, 256, 0, stream>>>(ei, deg, col);
    k_gemm1<<<(NN + 63) / 64, 256, 0, stream>>>(x, W1p, h1, a_src1, a_dst1);
    k_agg1<<<(NN + 3) / 4, 256, 0, stream>>>(deg, col, a_src1, a_dst1, h1, b1, h2pre);
    k_gemm2<<<(NN + 63) / 64, 256, 0, stream>>>(h2pre, W2p, as2, ad2, hL2, a_src2, a_dst2);
    k_agg2<<<(NN + 3) / 4, 256, 0, stream>>>(deg, col, a_src2, a_dst2, hL2, b2, hfin);
    k_pool<<<GG * SPLIT, 128, 0, stream>>>(gstart, hfin, pooled);
    k_head<<<GG, 128, 0, stream>>>(gstart, pooled, gfeat, Wg1, bg1, Wg2, bg2,
                                   Wc1, bc1, Wc2, bc2, out);
}

// Round 7
// 310.146 us; speedup vs baseline: 3.1730x; 1.0629x over previous
//
#include <hip/hip_runtime.h>
#include <hip/hip_bf16.h>

#define NN 50000
#define EE 400000
#define GG 64
#define CAP 96
#define SPLIT 16

typedef unsigned short u16;
typedef unsigned char u8;
typedef __attribute__((ext_vector_type(8))) short bf16x8;
typedef __attribute__((ext_vector_type(4))) float f32x4;
typedef __attribute__((ext_vector_type(2))) float f32x2;

// bf16 <-> f32 used ONLY for internal workspace tensors.
__device__ __forceinline__ float b2f(u16 u) {
    unsigned int x = ((unsigned int)u) << 16;
    return __uint_as_float(x);
}
__device__ __forceinline__ u16 f2b(float f) {
    unsigned int x = __float_as_uint(f);
    unsigned int r = x + 0x7fffu + ((x >> 16) & 1u);
    return (u16)(r >> 16);
}
// fp8 e4m3 (OCP) via HW converts — internal tensors h1, hL2 only.
__device__ __forceinline__ u8 f2fp8(float f) {
    return (u8)(__builtin_amdgcn_cvt_pk_fp8_f32(f, f, 0, false) & 0xFF);
}
__device__ __forceinline__ f32x2 fp8x2_f32(unsigned int v, bool hi) {
    return hi ? __builtin_amdgcn_cvt_pk_f32_fp8(v, true)
              : __builtin_amdgcn_cvt_pk_f32_fp8(v, false);
}
__device__ __forceinline__ float wred_sum(float v) {
    #pragma unroll
    for (int o = 32; o; o >>= 1) v += __shfl_xor(v, o, 64);
    return v;
}
__device__ __forceinline__ float lrelu(float v) { return v > 0.f ? v : 0.2f * v; }

// ---- init: degree=1 (self loop), seed CSR bucket with self loop. NO atomics.
__global__ void k_init(int* __restrict__ deg, int* __restrict__ col) {
    int n = blockIdx.x * 256 + threadIdx.x;
    if (n < NN) {
        deg[n] = 1;
        col[(size_t)n * CAP] = n;
    }
}

// ---- graph segment starts via binary search over sorted batch (no atomics)
__global__ void k_gstart(const int* __restrict__ batch, int* __restrict__ gstart) {
    int g = threadIdx.x;
    if (g <= GG) {
        int lo = 0, hi = NN;
        while (lo < hi) {
            int mid = (lo + hi) >> 1;
            if (batch[mid] < g) lo = mid + 1; else hi = mid;
        }
        gstart[g] = lo;
    }
}

// ---- bucket-append edges by dst
__global__ void k_edges(const int* __restrict__ ei, int* __restrict__ deg,
                        int* __restrict__ col) {
    int e = blockIdx.x * 256 + threadIdx.x;
    if (e < EE) {
        int s = ei[e];
        int d = ei[EE + e];
        int slot = atomicAdd(&deg[d], 1);
        if (slot < CAP) col[(size_t)d * CAP + slot] = s;
    }
}

// ---- prep W1: compute asW[k][h] = W1[:,head]@att (fp32) and pack
// [W1 | asW] into bf16 MFMA B-frag order, K padded 16->32 with zeros.
__global__ void k_prepW1(const float* __restrict__ W1,
                         const float* __restrict__ as1, const float* __restrict__ ad1,
                         u16* __restrict__ W1p) {
    __shared__ float asw[16][8];
    int t = threadIdx.x;
    if (t < 128) {
        int k = t >> 3, h = t & 7;
        int hd = h & 3;
        const float* att = (h >= 4) ? ad1 : as1;
        float s = 0.f;
        for (int c = 0; c < 128; c++) s += W1[k * 512 + hd * 128 + c] * att[hd * 128 + c];
        asw[k][h] = s;
    }
    __syncthreads();
    for (int idx = t; idx < 33 * 64 * 8; idx += 256) {
        int j = idx & 7, l = (idx >> 3) & 63, tt = idx >> 9;
        int quad = l >> 4, m = l & 15;
        int k = quad * 8 + j;
        float v = 0.f;
        if (k < 16) {
            if (tt < 32) v = W1[k * 512 + tt * 16 + m];
            else if (m < 8) v = asw[k][m];
        }
        W1p[idx] = f2b(v);
    }
}

// ---- pack W2 (fp32 [512][128]) into bf16 MFMA B-fragment order.
__global__ void k_cvtW2(const float* __restrict__ W2, u16* __restrict__ W2p) {
    int idx = blockIdx.x * 256 + threadIdx.x;  // 65536 total
    int j = idx & 7;
    int l = (idx >> 3) & 63;
    int ct = idx >> 9;
    int c = ct >> 3, tt = ct & 7;
    int k = c * 32 + (l >> 4) * 8 + j;
    int n = tt * 16 + (l & 15);
    W2p[idx] = f2b(W2[k * 128 + n]);
}

// ---- layer1 linear via MFMA: [h1(fp8) | a_src1 | a_dst1] = x @ [W1 | asW]
__global__ __launch_bounds__(256) void k_gemm1(
    const float* __restrict__ x, const u16* __restrict__ W1p,
    u8* __restrict__ h1, float* __restrict__ a_src1, float* __restrict__ a_dst1) {
    int tid = threadIdx.x;
    int wave = tid >> 6, l = tid & 63;
    int quad = l >> 4, m = l & 15;
    int row0 = blockIdx.x * 64 + wave * 16;
    int arow = row0 + m;
    int arow_c = arow < NN ? arow : (NN - 1);
    bf16x8 af;
    if (quad < 2) {
        const float* xp = x + arow_c * 16 + quad * 8;
        float4 x0 = *(const float4*)(xp);
        float4 x1 = *(const float4*)(xp + 4);
        u16 tmp[8] = {f2b(x0.x), f2b(x0.y), f2b(x0.z), f2b(x0.w),
                      f2b(x1.x), f2b(x1.y), f2b(x1.z), f2b(x1.w)};
        af = *(bf16x8*)tmp;
    } else {
        af = (bf16x8){0, 0, 0, 0, 0, 0, 0, 0};
    }
    const u16* bp = W1p + l * 8;
    f32x4 acc[33];
    #pragma unroll
    for (int tt = 0; tt < 33; tt++) acc[tt] = (f32x4){0.f, 0.f, 0.f, 0.f};
    #pragma unroll
    for (int tt = 0; tt < 33; tt++) {
        bf16x8 bf = *(const bf16x8*)(bp + (size_t)tt * 512);
        acc[tt] = __builtin_amdgcn_mfma_f32_16x16x32_bf16(af, bf, acc[tt], 0, 0, 0);
    }
    #pragma unroll
    for (int r = 0; r < 4; r++) {
        int row = row0 + quad * 4 + r;
        if (row >= NN) continue;
        #pragma unroll
        for (int tt = 0; tt < 32; tt++)
            h1[(size_t)row * 512 + tt * 16 + m] = f2fp8(acc[tt][r]);
        float v = acc[32][r];
        if (m < 4) a_src1[row * 4 + m] = v;
        else if (m < 8) a_dst1[row * 4 + (m - 4)] = v;
    }
}

// ---- layer1 attention: WAVE-PER-NODE, register softmax (no max pass —
// softmax shift-invariant, scores are O(10)), fp8 gather (8B/lane).
__global__ __launch_bounds__(256) void k_agg1(
    const int* __restrict__ deg, const int* __restrict__ col,
    const float* __restrict__ a_src1, const float* __restrict__ a_dst1,
    const u8* __restrict__ h1, const float* __restrict__ b1,
    u16* __restrict__ h2pre) {
    int t = threadIdx.x;
    int wave = t >> 6, l = t & 63;
    int n = blockIdx.x * 4 + wave;
    if (n >= NN) return;
    int dg = min(deg[n], CAP);
    int s0 = (l < dg) ? col[(size_t)n * CAP + l] : 0;
    int s1 = (l + 64 < dg) ? col[(size_t)n * CAP + l + 64] : 0;
    float4 ad = *(const float4*)(a_dst1 + n * 4);
    float4 e0, e1;
    {
        float4 as = *(const float4*)(a_src1 + (size_t)s0 * 4);
        e0.x = __expf(lrelu(as.x + ad.x)); e0.y = __expf(lrelu(as.y + ad.y));
        e0.z = __expf(lrelu(as.z + ad.z)); e0.w = __expf(lrelu(as.w + ad.w));
        if (l >= dg) e0 = (float4){0.f, 0.f, 0.f, 0.f};
    }
    {
        float4 as = *(const float4*)(a_src1 + (size_t)s1 * 4);
        e1.x = __expf(lrelu(as.x + ad.x)); e1.y = __expf(lrelu(as.y + ad.y));
        e1.z = __expf(lrelu(as.z + ad.z)); e1.w = __expf(lrelu(as.w + ad.w));
        if (l + 64 >= dg) e1 = (float4){0.f, 0.f, 0.f, 0.f};
    }
    float4 inv;
    inv.x = 1.0f / wred_sum(e0.x + e1.x);
    inv.y = 1.0f / wred_sum(e0.y + e1.y);
    inv.z = 1.0f / wred_sum(e0.z + e1.z);
    inv.w = 1.0f / wred_sum(e0.w + e1.w);
    e0.x *= inv.x; e0.y *= inv.y; e0.z *= inv.z; e0.w *= inv.w;
    e1.x *= inv.x; e1.y *= inv.y; e1.z *= inv.z; e1.w *= inv.w;
    int h = l >> 4;
    f32x2 acc[4] = {{0.f, 0.f}, {0.f, 0.f}, {0.f, 0.f}, {0.f, 0.f}};
    const u8* hb = h1 + l * 8;
    int jmax = min(dg, 64);
    for (int j = 0; j < jmax; j++) {
        int sj = __shfl(s0, j);
        float ax = __shfl(e0.x, j), ay = __shfl(e0.y, j);
        float az = __shfl(e0.z, j), aw = __shfl(e0.w, j);
        float al = h == 0 ? ax : (h == 1 ? ay : (h == 2 ? az : aw));
        uint2 u = *(const uint2*)(hb + (size_t)sj * 512);
        f32x2 p0 = fp8x2_f32(u.x, false), p1 = fp8x2_f32(u.x, true);
        f32x2 p2 = fp8x2_f32(u.y, false), p3 = fp8x2_f32(u.y, true);
        acc[0] += al * p0; acc[1] += al * p1;
        acc[2] += al * p2; acc[3] += al * p3;
    }
    for (int j = 64; j < dg; j++) {
        int sj = __shfl(s1, j - 64);
        float ax = __shfl(e1.x, j - 64), ay = __shfl(e1.y, j - 64);
        float az = __shfl(e1.z, j - 64), aw = __shfl(e1.w, j - 64);
        float al = h == 0 ? ax : (h == 1 ? ay : (h == 2 ? az : aw));
        uint2 u = *(const uint2*)(hb + (size_t)sj * 512);
        f32x2 p0 = fp8x2_f32(u.x, false), p1 = fp8x2_f32(u.x, true);
        f32x2 p2 = fp8x2_f32(u.y, false), p3 = fp8x2_f32(u.y, true);
        acc[0] += al * p0; acc[1] += al * p1;
        acc[2] += al * p2; acc[3] += al * p3;
    }
    float4 bA = *(const float4*)(b1 + l * 8);
    float4 bB = *(const float4*)(b1 + l * 8 + 4);
    float av[8] = {acc[0].x, acc[0].y, acc[1].x, acc[1].y,
                   acc[2].x, acc[2].y, acc[3].x, acc[3].y};
    float bb[8] = {bA.x, bA.y, bA.z, bA.w, bB.x, bB.y, bB.z, bB.w};
    u16 ov[8];
    #pragma unroll
    for (int k = 0; k < 8; k++) {
        float v = av[k] + bb[k];
        v = v > 0.f ? v : __expf(v) - 1.0f;
        ov[k] = f2b(v);
    }
    *(bf16x8*)(h2pre + (size_t)n * 512 + l * 8) = *(bf16x8*)ov;
}

// ---- layer2 linear via MFMA: hL2(fp8) = h2pre@W2, fused a_src2/a_dst2.
__global__ __launch_bounds__(256) void k_gemm2(
    const u16* __restrict__ h2pre, const u16* __restrict__ W2p,
    const float* __restrict__ as2, const float* __restrict__ ad2,
    u8* __restrict__ hL2, float* __restrict__ a_src2, float* __restrict__ a_dst2) {
    int t = threadIdx.x;
    int wave = t >> 6, l = t & 63;
    int quad = l >> 4, m = l & 15;
    int row0 = blockIdx.x * 64 + wave * 16;
    int arow = row0 + m;
    int arow_c = arow < NN ? arow : (NN - 1);
    const u16* aptr = h2pre + (size_t)arow_c * 512 + quad * 8;
    const u16* bptr = W2p + l * 8;
    f32x4 acc[8];
    #pragma unroll
    for (int tt = 0; tt < 8; tt++) acc[tt] = (f32x4){0.f, 0.f, 0.f, 0.f};
    for (int c = 0; c < 16; c++) {
        bf16x8 af = *(const bf16x8*)(aptr + c * 32);
        #pragma unroll
        for (int tt = 0; tt < 8; tt++) {
            bf16x8 bf = *(const bf16x8*)(bptr + (size_t)(c * 8 + tt) * 512);
            acc[tt] = __builtin_amdgcn_mfma_f32_16x16x32_bf16(af, bf, acc[tt], 0, 0, 0);
        }
    }
    float asv[8], adv[8];
    #pragma unroll
    for (int tt = 0; tt < 8; tt++) {
        int colc = tt * 16 + m;
        asv[tt] = as2[colc];
        adv[tt] = ad2[colc];
    }
    #pragma unroll
    for (int r = 0; r < 4; r++) {
        int row = row0 + quad * 4 + r;
        bool ok = row < NN;
        float rs = 0.f, rd = 0.f;
        #pragma unroll
        for (int tt = 0; tt < 8; tt++) {
            float v = acc[tt][r];
            if (ok) hL2[(size_t)row * 128 + tt * 16 + m] = f2fp8(v);
            rs += v * asv[tt];
            rd += v * adv[tt];
        }
        #pragma unroll
        for (int o = 1; o < 16; o <<= 1) {
            rs += __shfl_xor(rs, o, 64);
            rd += __shfl_xor(rd, o, 64);
        }
        if (ok && m == 0) { a_src2[row] = rs; a_dst2[row] = rd; }
    }
}

// ---- layer2 attention: WAVE-PER-NODE, no max pass, fp8 gather (2B/lane).
__global__ __launch_bounds__(256) void k_agg2(
    const int* __restrict__ deg, const int* __restrict__ col,
    const float* __restrict__ a_src2, const float* __restrict__ a_dst2,
    const u8* __restrict__ hL2, const float* __restrict__ b2v,
    float* __restrict__ hfin) {
    int t = threadIdx.x;
    int wave = t >> 6, l = t & 63;
    int n = blockIdx.x * 4 + wave;
    if (n >= NN) return;
    int dg = min(deg[n], CAP);
    int s0 = (l < dg) ? col[(size_t)n * CAP + l] : 0;
    int s1 = (l + 64 < dg) ? col[(size_t)n * CAP + l + 64] : 0;
    float ad = a_dst2[n];
    float e0 = (l < dg) ? __expf(lrelu(a_src2[s0] + ad)) : 0.f;
    float e1 = (l + 64 < dg) ? __expf(lrelu(a_src2[s1] + ad)) : 0.f;
    float inv = 1.0f / wred_sum(e0 + e1);
    e0 *= inv; e1 *= inv;
    f32x2 acc = {0.f, 0.f};
    const u8* hb = hL2 + l * 2;
    int jmax = min(dg, 64);
    for (int j = 0; j < jmax; j++) {
        int sj = __shfl(s0, j);
        float al = __shfl(e0, j);
        unsigned int u = *(const u16*)(hb + (size_t)sj * 128);
        acc += al * fp8x2_f32(u, false);
    }
    for (int j = 64; j < dg; j++) {
        int sj = __shfl(s1, j - 64);
        float al = __shfl(e1, j - 64);
        unsigned int u = *(const u16*)(hb + (size_t)sj * 128);
        acc += al * fp8x2_f32(u, false);
    }
    float o0 = acc.x + b2v[2 * l];     o0 = o0 > 0.f ? o0 : __expf(o0) - 1.0f;
    float o1 = acc.y + b2v[2 * l + 1]; o1 = o1 > 0.f ? o1 : __expf(o1) - 1.0f;
    float2 ov; ov.x = o0; ov.y = o1;
    *(float2*)(hfin + (size_t)n * 128 + 2 * l) = ov;
}

// ---- parallel mean-pool partials: grid GG*SPLIT, atomicAdd into pooled
__global__ __launch_bounds__(128) void k_pool(
    const int* __restrict__ gstart, const float* __restrict__ hfin,
    float* __restrict__ pooled) {
    int g = blockIdx.x / SPLIT, i = blockIdx.x % SPLIT, t = threadIdx.x;
    int s0 = gstart[g], s1 = gstart[g + 1];
    int len = s1 - s0;
    int chunk = (len + SPLIT - 1) / SPLIT;
    int a = s0 + i * chunk;
    int b = min(a + chunk, s1);
    if (a >= b) return;
    float acc = 0.f;
    for (int n = a; n < b; n++) acc += hfin[(size_t)n * 128 + t];
    atomicAdd(&pooled[g * 128 + t], acc);
}

// ---- graph MLP + classifier (pooled already summed)
__global__ __launch_bounds__(128) void k_head(
    const int* __restrict__ gstart, const float* __restrict__ pooled,
    const float* __restrict__ gfeat,
    const float* __restrict__ Wg1, const float* __restrict__ bg1,
    const float* __restrict__ Wg2, const float* __restrict__ bg2,
    const float* __restrict__ Wc1, const float* __restrict__ bc1,
    const float* __restrict__ Wc2, const float* __restrict__ bc2,
    float* __restrict__ out) {
    __shared__ float z[160];
    __shared__ float hg[32];
    __shared__ float c1b[128];
    int g = blockIdx.x, t = threadIdx.x;
    float cntf = (float)(gstart[g + 1] - gstart[g]);
    z[t] = pooled[g * 128 + t] / fmaxf(cntf, 1.0f);
    if (t < 32) {
        float a = bg1[t];
        for (int i = 0; i < 10; i++) a += gfeat[g * 10 + i] * Wg1[i * 32 + t];
        hg[t] = fmaxf(a, 0.f);
    }
    __syncthreads();
    if (t < 32) {
        float a = bg2[t];
        for (int i = 0; i < 32; i++) a += hg[i] * Wg2[i * 32 + t];
        z[128 + t] = a;
    }
    __syncthreads();
    float a = bc1[t];
    for (int i = 0; i < 160; i++) a += z[i] * Wc1[i * 128 + t];
    c1b[t] = fmaxf(a, 0.f);
    __syncthreads();
    if (t < 6) {
        float o = bc2[t];
        for (int i = 0; i < 128; i++) o += c1b[i] * Wc2[i * 6 + t];
        out[g * 6 + t] = o;
    }
}

extern "C" void kernel_launch(void* const* d_in, const int* in_sizes, int n_in,
                              void* d_out, int out_size, void* d_ws, size_t ws_size,
                              hipStream_t stream) {
    const float* x     = (const float*)d_in[0];
    const int*   ei    = (const int*)d_in[1];
    const int*   batch = (const int*)d_in[2];
    const float* gfeat = (const float*)d_in[3];
    const float* W1    = (const float*)d_in[4];
    const float* as1   = (const float*)d_in[5];
    const float* ad1   = (const float*)d_in[6];
    const float* b1    = (const float*)d_in[7];
    const float* W2    = (const float*)d_in[8];
    const float* as2   = (const float*)d_in[9];
    const float* ad2   = (const float*)d_in[10];
    const float* b2    = (const float*)d_in[11];
    const float* Wg1   = (const float*)d_in[12];
    const float* bg1   = (const float*)d_in[13];
    const float* Wg2   = (const float*)d_in[14];
    const float* bg2   = (const float*)d_in[15];
    const float* Wc1   = (const float*)d_in[16];
    const float* bc1   = (const float*)d_in[17];
    const float* Wc2   = (const float*)d_in[18];
    const float* bc2   = (const float*)d_in[19];
    float* out = (float*)d_out;

    size_t off = 0;
    char* base = (char*)d_ws;
    auto take = [&](size_t nbytes) -> char* {
        char* p = base + off;
        off = (off + nbytes + 255) & ~(size_t)255;
        return p;
    };
    u8*    h1     = (u8*)take((size_t)NN * 512);
    u16*   h2pre  = (u16*)take((size_t)NN * 512 * 2);
    u8*    hL2    = (u8*)take((size_t)NN * 128);
    float* hfin   = (float*)take((size_t)NN * 128 * 4);
    float* a_src1 = (float*)take((size_t)NN * 4 * 4);
    float* a_dst1 = (float*)take((size_t)NN * 4 * 4);
    float* a_src2 = (float*)take((size_t)NN * 4);
    float* a_dst2 = (float*)take((size_t)NN * 4);
    int*   deg    = (int*)take((size_t)NN * 4);
    int*   col    = (int*)take((size_t)NN * CAP * 4);
    float* pooled = (float*)take(GG * 128 * 4);
    int*   gstart = (int*)take((GG + 1) * 4);
    u16*   W2p    = (u16*)take((size_t)512 * 128 * 2);
    u16*   W1p    = (u16*)take((size_t)33 * 64 * 8 * 2);
    (void)ws_size; (void)in_sizes; (void)n_in; (void)out_size;

    hipMemsetAsync(pooled, 0, GG * 128 * 4, stream);
    k_init<<<(NN + 255) / 256, 256, 0, stream>>>(deg, col);
    k_gstart<<<1, 128, 0, stream>>>(batch, gstart);
    k_prepW1<<<1, 256, 0, stream>>>(W1, as1, ad1, W1p);
    k_cvtW2<<<256, 256, 0, stream>>>(W2, W2p);
    k_edges<<<(EE + 255) / 256, 256, 0, stream>>>(ei, deg, col);
    k_gemm1<<<(NN + 63) / 64, 256, 0, stream>>>(x, W1p, h1, a_src1, a_dst1);
    k_agg1<<<(NN + 3) / 4, 256, 0, stream>>>(deg, col, a_src1, a_dst1, h1, b1, h2pre);
    k_gemm2<<<(NN + 63) / 64, 256, 0, stream>>>(h2pre, W2p, as2, ad2, hL2, a_src2, a_dst2);
    k_agg2<<<(NN + 3) / 4, 256, 0, stream>>>(deg, col, a_src2, a_dst2, hL2, b2, hfin);
    k_pool<<<GG * SPLIT, 128, 0, stream>>>(gstart, hfin, pooled);
    k_head<<<GG, 128, 0, stream>>>(gstart, pooled, gfeat, Wg1, bg1, Wg2, bg2,
                                   Wc1, bc1, Wc2, bc2, out);
}

// Round 8
// 299.111 us; speedup vs baseline: 3.2900x; 1.0369x over previous
//
#include <hip/hip_runtime.h>
#include <hip/hip_bf16.h>

#define NN 50000
#define EE 400000
#define GG 64
#define CAP 96
#define SPLIT 16

typedef unsigned short u16;
typedef unsigned char u8;
typedef __attribute__((ext_vector_type(8))) short bf16x8;
typedef __attribute__((ext_vector_type(4))) float f32x4;
typedef __attribute__((ext_vector_type(2))) float f32x2;

__device__ __forceinline__ float b2f(u16 u) {
    unsigned int x = ((unsigned int)u) << 16;
    return __uint_as_float(x);
}
__device__ __forceinline__ u16 f2b(float f) {
    unsigned int x = __float_as_uint(f);
    unsigned int r = x + 0x7fffu + ((x >> 16) & 1u);
    return (u16)(r >> 16);
}
// fp8 e4m3 (OCP) via HW converts — internal tensors h1, hL2 only.
__device__ __forceinline__ u8 f2fp8(float f) {
    return (u8)(__builtin_amdgcn_cvt_pk_fp8_f32(f, f, 0, false) & 0xFF);
}
__device__ __forceinline__ f32x2 fp8x2_f32(unsigned int v, bool hi) {
    return hi ? __builtin_amdgcn_cvt_pk_f32_fp8(v, true)
              : __builtin_amdgcn_cvt_pk_f32_fp8(v, false);
}
__device__ __forceinline__ float wred_sum(float v) {
    #pragma unroll
    for (int o = 32; o; o >>= 1) v += __shfl_xor(v, o, 64);
    return v;
}
__device__ __forceinline__ float lrelu(float v) { return v > 0.f ? v : 0.2f * v; }

// ---- init
__global__ void k_init(int* __restrict__ deg, int* __restrict__ col) {
    int n = blockIdx.x * 256 + threadIdx.x;
    if (n < NN) {
        deg[n] = 1;
        col[(size_t)n * CAP] = n;
    }
}

// ---- graph segment starts via binary search over sorted batch
__global__ void k_gstart(const int* __restrict__ batch, int* __restrict__ gstart) {
    int g = threadIdx.x;
    if (g <= GG) {
        int lo = 0, hi = NN;
        while (lo < hi) {
            int mid = (lo + hi) >> 1;
            if (batch[mid] < g) lo = mid + 1; else hi = mid;
        }
        gstart[g] = lo;
    }
}

// ---- bucket-append edges by dst
__global__ void k_edges(const int* __restrict__ ei, int* __restrict__ deg,
                        int* __restrict__ col) {
    int e = blockIdx.x * 256 + threadIdx.x;
    if (e < EE) {
        int s = ei[e];
        int d = ei[EE + e];
        int slot = atomicAdd(&deg[d], 1);
        if (slot < CAP) col[(size_t)d * CAP + slot] = s;
    }
}

// ---- prep W1: [W1 | asW] in bf16 MFMA B-frag order, K padded 16->32.
__global__ void k_prepW1(const float* __restrict__ W1,
                         const float* __restrict__ as1, const float* __restrict__ ad1,
                         u16* __restrict__ W1p) {
    __shared__ float asw[16][8];
    int t = threadIdx.x;
    if (t < 128) {
        int k = t >> 3, h = t & 7;
        int hd = h & 3;
        const float* att = (h >= 4) ? ad1 : as1;
        float s = 0.f;
        for (int c = 0; c < 128; c++) s += W1[k * 512 + hd * 128 + c] * att[hd * 128 + c];
        asw[k][h] = s;
    }
    __syncthreads();
    for (int idx = t; idx < 33 * 64 * 8; idx += 256) {
        int j = idx & 7, l = (idx >> 3) & 63, tt = idx >> 9;
        int quad = l >> 4, m = l & 15;
        int k = quad * 8 + j;
        float v = 0.f;
        if (k < 16) {
            if (tt < 32) v = W1[k * 512 + tt * 16 + m];
            else if (m < 8) v = asw[k][m];
        }
        W1p[idx] = f2b(v);
    }
}

// ---- pack W2 into bf16 MFMA B-fragment order.
__global__ void k_cvtW2(const float* __restrict__ W2, u16* __restrict__ W2p) {
    int idx = blockIdx.x * 256 + threadIdx.x;
    int j = idx & 7;
    int l = (idx >> 3) & 63;
    int ct = idx >> 9;
    int c = ct >> 3, tt = ct & 7;
    int k = c * 32 + (l >> 4) * 8 + j;
    int n = tt * 16 + (l & 15);
    W2p[idx] = f2b(W2[k * 128 + n]);
}

// ---- layer1 linear via MFMA: [h1(fp8) | a_src1 | a_dst1] = x @ [W1 | asW]
__global__ __launch_bounds__(256) void k_gemm1(
    const float* __restrict__ x, const u16* __restrict__ W1p,
    u8* __restrict__ h1, float* __restrict__ a_src1, float* __restrict__ a_dst1) {
    int tid = threadIdx.x;
    int wave = tid >> 6, l = tid & 63;
    int quad = l >> 4, m = l & 15;
    int row0 = blockIdx.x * 64 + wave * 16;
    int arow = row0 + m;
    int arow_c = arow < NN ? arow : (NN - 1);
    bf16x8 af;
    if (quad < 2) {
        const float* xp = x + arow_c * 16 + quad * 8;
        float4 x0 = *(const float4*)(xp);
        float4 x1 = *(const float4*)(xp + 4);
        u16 tmp[8] = {f2b(x0.x), f2b(x0.y), f2b(x0.z), f2b(x0.w),
                      f2b(x1.x), f2b(x1.y), f2b(x1.z), f2b(x1.w)};
        af = *(bf16x8*)tmp;
    } else {
        af = (bf16x8){0, 0, 0, 0, 0, 0, 0, 0};
    }
    const u16* bp = W1p + l * 8;
    f32x4 acc[33];
    #pragma unroll
    for (int tt = 0; tt < 33; tt++) acc[tt] = (f32x4){0.f, 0.f, 0.f, 0.f};
    #pragma unroll
    for (int tt = 0; tt < 33; tt++) {
        bf16x8 bf = *(const bf16x8*)(bp + (size_t)tt * 512);
        acc[tt] = __builtin_amdgcn_mfma_f32_16x16x32_bf16(af, bf, acc[tt], 0, 0, 0);
    }
    #pragma unroll
    for (int r = 0; r < 4; r++) {
        int row = row0 + quad * 4 + r;
        if (row >= NN) continue;
        #pragma unroll
        for (int tt = 0; tt < 32; tt++)
            h1[(size_t)row * 512 + tt * 16 + m] = f2fp8(acc[tt][r]);
        float v = acc[32][r];
        if (m < 4) a_src1[row * 4 + m] = v;
        else if (m < 8) a_dst1[row * 4 + (m - 4)] = v;
    }
}

// ---- layer1 attention: WAVE-PER-NODE. Softmax in registers (no max pass);
// indices+alphas staged in LDS (same-wave, no barrier); gather loop fetches
// 4 rows/iter via 2 independent 16B loads (lane half = row parity).
__global__ __launch_bounds__(256) void k_agg1(
    const int* __restrict__ deg, const int* __restrict__ col,
    const float* __restrict__ a_src1, const float* __restrict__ a_dst1,
    const u8* __restrict__ h1, const float* __restrict__ b1,
    u16* __restrict__ h2pre) {
    __shared__ int   scolS[4][CAP];
    __shared__ float alphaS[4][CAP][4];
    int t = threadIdx.x;
    int wave = t >> 6, l = t & 63;
    int n = blockIdx.x * 4 + wave;
    if (n >= NN) return;
    int dg = min(deg[n], CAP);
    int s0 = (l < dg) ? col[(size_t)n * CAP + l] : 0;
    int s1 = (l + 64 < dg) ? col[(size_t)n * CAP + l + 64] : 0;
    float4 ad = *(const float4*)(a_dst1 + n * 4);
    float4 e0, e1;
    {
        float4 as = *(const float4*)(a_src1 + (size_t)s0 * 4);
        e0.x = __expf(lrelu(as.x + ad.x)); e0.y = __expf(lrelu(as.y + ad.y));
        e0.z = __expf(lrelu(as.z + ad.z)); e0.w = __expf(lrelu(as.w + ad.w));
        if (l >= dg) e0 = (float4){0.f, 0.f, 0.f, 0.f};
    }
    {
        float4 as = *(const float4*)(a_src1 + (size_t)s1 * 4);
        e1.x = __expf(lrelu(as.x + ad.x)); e1.y = __expf(lrelu(as.y + ad.y));
        e1.z = __expf(lrelu(as.z + ad.z)); e1.w = __expf(lrelu(as.w + ad.w));
        if (l + 64 >= dg) e1 = (float4){0.f, 0.f, 0.f, 0.f};
    }
    float4 inv;
    inv.x = 1.0f / wred_sum(e0.x + e1.x);
    inv.y = 1.0f / wred_sum(e0.y + e1.y);
    inv.z = 1.0f / wred_sum(e0.z + e1.z);
    inv.w = 1.0f / wred_sum(e0.w + e1.w);
    if (l < dg) {
        scolS[wave][l] = s0;
        float4 a4; a4.x = e0.x * inv.x; a4.y = e0.y * inv.y;
        a4.z = e0.z * inv.z; a4.w = e0.w * inv.w;
        *(float4*)&alphaS[wave][l][0] = a4;
    }
    if (l + 64 < dg) {
        scolS[wave][l + 64] = s1;
        float4 a4; a4.x = e1.x * inv.x; a4.y = e1.y * inv.y;
        a4.z = e1.z * inv.z; a4.w = e1.w * inv.w;
        *(float4*)&alphaS[wave][l + 64][0] = a4;
    }
    // gather: lane covers channels (l&31)*16..+15 of row-half l>>5
    int half = l >> 5;
    int lc = l & 31;
    int c0 = lc * 16;
    int hh = lc >> 3;           // head of this channel slice
    f32x2 acc[8];
    #pragma unroll
    for (int k = 0; k < 8; k++) acc[k] = (f32x2){0.f, 0.f};
    int iters = (dg + 3) >> 2;
    for (int j = 0; j < iters; j++) {
        int eA = 4 * j + half;
        int eB = 4 * j + 2 + half;
        int sA = 0; float aA = 0.f;
        if (eA < dg) { sA = scolS[wave][eA]; aA = alphaS[wave][eA][hh]; }
        int sB = 0; float aB = 0.f;
        if (eB < dg) { sB = scolS[wave][eB]; aB = alphaS[wave][eB][hh]; }
        uint4 uA = *(const uint4*)(h1 + (size_t)sA * 512 + c0);
        uint4 uB = *(const uint4*)(h1 + (size_t)sB * 512 + c0);
        unsigned int wa[4] = {uA.x, uA.y, uA.z, uA.w};
        unsigned int wb[4] = {uB.x, uB.y, uB.z, uB.w};
        #pragma unroll
        for (int w = 0; w < 4; w++) {
            acc[2 * w]     += aA * fp8x2_f32(wa[w], false);
            acc[2 * w + 1] += aA * fp8x2_f32(wa[w], true);
        }
        #pragma unroll
        for (int w = 0; w < 4; w++) {
            acc[2 * w]     += aB * fp8x2_f32(wb[w], false);
            acc[2 * w + 1] += aB * fp8x2_f32(wb[w], true);
        }
    }
    // combine the two row-halves (same channels live in lanes l and l^32)
    #pragma unroll
    for (int k = 0; k < 8; k++) {
        acc[k].x += __shfl_xor(acc[k].x, 32, 64);
        acc[k].y += __shfl_xor(acc[k].y, 32, 64);
    }
    // lane writes 8 channels: base lc*16 + half*8, acc pairs half*4..half*4+3
    int ch0 = c0 + half * 8;
    float4 bA = *(const float4*)(b1 + ch0);
    float4 bB = *(const float4*)(b1 + ch0 + 4);
    float bb[8] = {bA.x, bA.y, bA.z, bA.w, bB.x, bB.y, bB.z, bB.w};
    u16 ov[8];
    #pragma unroll
    for (int k = 0; k < 8; k++) {
        int ai = half * 4 + (k >> 1);
        float v = ((k & 1) ? acc[ai].y : acc[ai].x) + bb[k];
        v = v > 0.f ? v : __expf(v) - 1.0f;
        ov[k] = f2b(v);
    }
    *(bf16x8*)(h2pre + (size_t)n * 512 + ch0) = *(bf16x8*)ov;
}

// ---- layer2 linear via MFMA: hL2(fp8) = h2pre@W2, fused a_src2/a_dst2.
__global__ __launch_bounds__(256) void k_gemm2(
    const u16* __restrict__ h2pre, const u16* __restrict__ W2p,
    const float* __restrict__ as2, const float* __restrict__ ad2,
    u8* __restrict__ hL2, float* __restrict__ a_src2, float* __restrict__ a_dst2) {
    int t = threadIdx.x;
    int wave = t >> 6, l = t & 63;
    int quad = l >> 4, m = l & 15;
    int row0 = blockIdx.x * 64 + wave * 16;
    int arow = row0 + m;
    int arow_c = arow < NN ? arow : (NN - 1);
    const u16* aptr = h2pre + (size_t)arow_c * 512 + quad * 8;
    const u16* bptr = W2p + l * 8;
    f32x4 acc[8];
    #pragma unroll
    for (int tt = 0; tt < 8; tt++) acc[tt] = (f32x4){0.f, 0.f, 0.f, 0.f};
    for (int c = 0; c < 16; c++) {
        bf16x8 af = *(const bf16x8*)(aptr + c * 32);
        #pragma unroll
        for (int tt = 0; tt < 8; tt++) {
            bf16x8 bf = *(const bf16x8*)(bptr + (size_t)(c * 8 + tt) * 512);
            acc[tt] = __builtin_amdgcn_mfma_f32_16x16x32_bf16(af, bf, acc[tt], 0, 0, 0);
        }
    }
    float asv[8], adv[8];
    #pragma unroll
    for (int tt = 0; tt < 8; tt++) {
        int colc = tt * 16 + m;
        asv[tt] = as2[colc];
        adv[tt] = ad2[colc];
    }
    #pragma unroll
    for (int r = 0; r < 4; r++) {
        int row = row0 + quad * 4 + r;
        bool ok = row < NN;
        float rs = 0.f, rd = 0.f;
        #pragma unroll
        for (int tt = 0; tt < 8; tt++) {
            float v = acc[tt][r];
            if (ok) hL2[(size_t)row * 128 + tt * 16 + m] = f2fp8(v);
            rs += v * asv[tt];
            rd += v * adv[tt];
        }
        #pragma unroll
        for (int o = 1; o < 16; o <<= 1) {
            rs += __shfl_xor(rs, o, 64);
            rd += __shfl_xor(rd, o, 64);
        }
        if (ok && m == 0) { a_src2[row] = rs; a_dst2[row] = rd; }
    }
}

// ---- layer2 attention: WAVE-PER-NODE, 8 rows/iter (16B per lane-octet).
__global__ __launch_bounds__(256) void k_agg2(
    const int* __restrict__ deg, const int* __restrict__ col,
    const float* __restrict__ a_src2, const float* __restrict__ a_dst2,
    const u8* __restrict__ hL2, const float* __restrict__ b2v,
    float* __restrict__ hfin) {
    __shared__ int   scolS[4][CAP];
    __shared__ float alS[4][CAP];
    int t = threadIdx.x;
    int wave = t >> 6, l = t & 63;
    int n = blockIdx.x * 4 + wave;
    if (n >= NN) return;
    int dg = min(deg[n], CAP);
    int s0 = (l < dg) ? col[(size_t)n * CAP + l] : 0;
    int s1 = (l + 64 < dg) ? col[(size_t)n * CAP + l + 64] : 0;
    float ad = a_dst2[n];
    float e0 = (l < dg) ? __expf(lrelu(a_src2[s0] + ad)) : 0.f;
    float e1 = (l + 64 < dg) ? __expf(lrelu(a_src2[s1] + ad)) : 0.f;
    float inv = 1.0f / wred_sum(e0 + e1);
    if (l < dg) { scolS[wave][l] = s0; alS[wave][l] = e0 * inv; }
    if (l + 64 < dg) { scolS[wave][l + 64] = s1; alS[wave][l + 64] = e1 * inv; }
    int grp = l >> 3;        // 0..7: which row of the octet
    int lc = l & 7;          // channel slice
    int c0 = lc * 16;
    f32x2 acc[8];
    #pragma unroll
    for (int k = 0; k < 8; k++) acc[k] = (f32x2){0.f, 0.f};
    int iters = (dg + 7) >> 3;
    for (int j = 0; j < iters; j++) {
        int e = 8 * j + grp;
        int s = 0; float a = 0.f;
        if (e < dg) { s = scolS[wave][e]; a = alS[wave][e]; }
        uint4 u = *(const uint4*)(hL2 + (size_t)s * 128 + c0);
        unsigned int w4[4] = {u.x, u.y, u.z, u.w};
        #pragma unroll
        for (int w = 0; w < 4; w++) {
            acc[2 * w]     += a * fp8x2_f32(w4[w], false);
            acc[2 * w + 1] += a * fp8x2_f32(w4[w], true);
        }
    }
    // reduce across the 8 row-groups (xor 8,16,32)
    #pragma unroll
    for (int o = 8; o < 64; o <<= 1) {
        #pragma unroll
        for (int k = 0; k < 8; k++) {
            acc[k].x += __shfl_xor(acc[k].x, o, 64);
            acc[k].y += __shfl_xor(acc[k].y, o, 64);
        }
    }
    // lane writes channel pair c0 + grp*2
    int ch = c0 + grp * 2;
    float o0 = acc[grp].x + b2v[ch];
    float o1 = acc[grp].y + b2v[ch + 1];
    o0 = o0 > 0.f ? o0 : __expf(o0) - 1.0f;
    o1 = o1 > 0.f ? o1 : __expf(o1) - 1.0f;
    float2 ov; ov.x = o0; ov.y = o1;
    *(float2*)(hfin + (size_t)n * 128 + ch) = ov;
}

// ---- parallel mean-pool partials
__global__ __launch_bounds__(128) void k_pool(
    const int* __restrict__ gstart, const float* __restrict__ hfin,
    float* __restrict__ pooled) {
    int g = blockIdx.x / SPLIT, i = blockIdx.x % SPLIT, t = threadIdx.x;
    int s0 = gstart[g], s1 = gstart[g + 1];
    int len = s1 - s0;
    int chunk = (len + SPLIT - 1) / SPLIT;
    int a = s0 + i * chunk;
    int b = min(a + chunk, s1);
    if (a >= b) return;
    float acc = 0.f;
    for (int n = a; n < b; n++) acc += hfin[(size_t)n * 128 + t];
    atomicAdd(&pooled[g * 128 + t], acc);
}

// ---- graph MLP + classifier
__global__ __launch_bounds__(128) void k_head(
    const int* __restrict__ gstart, const float* __restrict__ pooled,
    const float* __restrict__ gfeat,
    const float* __restrict__ Wg1, const float* __restrict__ bg1,
    const float* __restrict__ Wg2, const float* __restrict__ bg2,
    const float* __restrict__ Wc1, const float* __restrict__ bc1,
    const float* __restrict__ Wc2, const float* __restrict__ bc2,
    float* __restrict__ out) {
    __shared__ float z[160];
    __shared__ float hg[32];
    __shared__ float c1b[128];
    int g = blockIdx.x, t = threadIdx.x;
    float cntf = (float)(gstart[g + 1] - gstart[g]);
    z[t] = pooled[g * 128 + t] / fmaxf(cntf, 1.0f);
    if (t < 32) {
        float a = bg1[t];
        for (int i = 0; i < 10; i++) a += gfeat[g * 10 + i] * Wg1[i * 32 + t];
        hg[t] = fmaxf(a, 0.f);
    }
    __syncthreads();
    if (t < 32) {
        float a = bg2[t];
        for (int i = 0; i < 32; i++) a += hg[i] * Wg2[i * 32 + t];
        z[128 + t] = a;
    }
    __syncthreads();
    float a = bc1[t];
    for (int i = 0; i < 160; i++) a += z[i] * Wc1[i * 128 + t];
    c1b[t] = fmaxf(a, 0.f);
    __syncthreads();
    if (t < 6) {
        float o = bc2[t];
        for (int i = 0; i < 128; i++) o += c1b[i] * Wc2[i * 6 + t];
        out[g * 6 + t] = o;
    }
}

extern "C" void kernel_launch(void* const* d_in, const int* in_sizes, int n_in,
                              void* d_out, int out_size, void* d_ws, size_t ws_size,
                              hipStream_t stream) {
    const float* x     = (const float*)d_in[0];
    const int*   ei    = (const int*)d_in[1];
    const int*   batch = (const int*)d_in[2];
    const float* gfeat = (const float*)d_in[3];
    const float* W1    = (const float*)d_in[4];
    const float* as1   = (const float*)d_in[5];
    const float* ad1   = (const float*)d_in[6];
    const float* b1    = (const float*)d_in[7];
    const float* W2    = (const float*)d_in[8];
    const float* as2   = (const float*)d_in[9];
    const float* ad2   = (const float*)d_in[10];
    const float* b2    = (const float*)d_in[11];
    const float* Wg1   = (const float*)d_in[12];
    const float* bg1   = (const float*)d_in[13];
    const float* Wg2   = (const float*)d_in[14];
    const float* bg2   = (const float*)d_in[15];
    const float* Wc1   = (const float*)d_in[16];
    const float* bc1   = (const float*)d_in[17];
    const float* Wc2   = (const float*)d_in[18];
    const float* bc2   = (const float*)d_in[19];
    float* out = (float*)d_out;

    size_t off = 0;
    char* base = (char*)d_ws;
    auto take = [&](size_t nbytes) -> char* {
        char* p = base + off;
        off = (off + nbytes + 255) & ~(size_t)255;
        return p;
    };
    u8*    h1     = (u8*)take((size_t)NN * 512);
    u16*   h2pre  = (u16*)take((size_t)NN * 512 * 2);
    u8*    hL2    = (u8*)take((size_t)NN * 128);
    float* hfin   = (float*)take((size_t)NN * 128 * 4);
    float* a_src1 = (float*)take((size_t)NN * 4 * 4);
    float* a_dst1 = (float*)take((size_t)NN * 4 * 4);
    float* a_src2 = (float*)take((size_t)NN * 4);
    float* a_dst2 = (float*)take((size_t)NN * 4);
    int*   deg    = (int*)take((size_t)NN * 4);
    int*   col    = (int*)take((size_t)NN * CAP * 4);
    float* pooled = (float*)take(GG * 128 * 4);
    int*   gstart = (int*)take((GG + 1) * 4);
    u16*   W2p    = (u16*)take((size_t)512 * 128 * 2);
    u16*   W1p    = (u16*)take((size_t)33 * 64 * 8 * 2);
    (void)ws_size; (void)in_sizes; (void)n_in; (void)out_size;

    hipMemsetAsync(pooled, 0, GG * 128 * 4, stream);
    k_init<<<(NN + 255) / 256, 256, 0, stream>>>(deg, col);
    k_gstart<<<1, 128, 0, stream>>>(batch, gstart);
    k_prepW1<<<1, 256, 0, stream>>>(W1, as1, ad1, W1p);
    k_cvtW2<<<256, 256, 0, stream>>>(W2, W2p);
    k_edges<<<(EE + 255) / 256, 256, 0, stream>>>(ei, deg, col);
    k_gemm1<<<(NN + 63) / 64, 256, 0, stream>>>(x, W1p, h1, a_src1, a_dst1);
    k_agg1<<<(NN + 3) / 4, 256, 0, stream>>>(deg, col, a_src1, a_dst1, h1, b1, h2pre);
    k_gemm2<<<(NN + 63) / 64, 256, 0, stream>>>(h2pre, W2p, as2, ad2, hL2, a_src2, a_dst2);
    k_agg2<<<(NN + 3) / 4, 256, 0, stream>>>(deg, col, a_src2, a_dst2, hL2, b2, hfin);
    k_pool<<<GG * SPLIT, 128, 0, stream>>>(gstart, hfin, pooled);
    k_head<<<GG, 128, 0, stream>>>(gstart, pooled, gfeat, Wg1, bg1, Wg2, bg2,
                                   Wc1, bc1, Wc2, bc2, out);
}